// Round 4
// baseline (928.683 us; speedup 1.0000x reference)
//
#include <hip/hip_runtime.h>
#include <hip/hip_bf16.h>

typedef unsigned short u16;

#define NN 9
#define DX 128
#define KP 64
#define LL 32
#define NALL 100000

// ---------- cross-kernel tables as typed device globals ----------
__device__ __align__(16) float g_tnx[LL * DX];       // normalized theta_x [l][d]
__device__ __align__(16) float g_tns[LL * NN];       // normalized theta_s [l][j]
__device__ __align__(16) float g_hprt[DX * KP];      // h_proto_root^T [d][k]
__device__ __align__(16) float g_hprn[KP];           // ||h_proto_root||^2 [k]
__device__ __align__(16) float g_hpt[32 * KP];       // hp^T [j][k]
__device__ __align__(16) float g_rpst[NN * KP];      // sorted proto_rad [m][k]
__device__ __align__(16) u16   g_ppxt[LL * NN * KP]; // sorted proto proj (feat) bf16 [(l*9+m)][k]
__device__ __align__(16) u16   g_ppst[LL * NN * KP]; // sorted proto proj (str)  bf16

__device__ __forceinline__ float bf2f(u16 u) {
    union { unsigned u; float f; } v; v.u = ((unsigned)u) << 16; return v.f;
}
__device__ __forceinline__ u16 f2bf(float f) {
    __hip_bfloat16 h = __float2bfloat16(f);
    union { __hip_bfloat16 h; u16 u; } v; v.h = h; return v.u;
}
// dtype-robust load: f32!=0 -> buffer is float32, else bf16
__device__ __forceinline__ float ldv(const void* p, int i, int f32) {
    return f32 ? ((const float*)p)[i] : bf2f(((const u16*)p)[i]);
}
__device__ __forceinline__ float sigmoidf(float x) { return 1.f / (1.f + expf(-x)); }

// branch-free stable rank of 9 values (tie -> lower original index first)
__device__ __forceinline__ void rank9(const float* v, int* r) {
#pragma unroll
    for (int m = 0; m < 9; m++) {
        int rk = 0;
#pragma unroll
        for (int n = 0; n < 9; n++)
            rk += (v[n] < v[m]) || (v[n] == v[m] && n < m);
        r[m] = rk;
    }
}

// ---------- shared memory layout (61440 B static) ----------
struct SMem {
    u16*   Wl;     // [0,32768)   x_lin_w bf16, 128x128
    float* xs;     // [32768,37888) gathered input rows 10x128
    float* tnx;    // [37888,54400) theta_x normalized, padded ld=129
    float* hX;     // [54400,59520) h rows 10x128
    int*      idxl;   // 10
    unsigned* adjr;   // 10
    float*    vmsk;   // 9
    float*    df;     // 100
    float*    tns;    // 288
    float*    sc;     // 4: [0]=n+1e-9 [1]=hrn [2]=alpha
    // phase-B scratch overlapping Wl region [0,32768) (Wl dead after lin)
    float *hst, *hsn, *pbS, *As, *Wsw, *t1s, *pbX, *Ax, *Wxw, *t1x;
    float *redA, *redB, *redC, *dradA, *hbv, *hpool, *rbss, *wrad;
};
__device__ __forceinline__ SMem make_smem(unsigned char* sm) {
    SMem s;
    s.Wl   = (u16*)sm;
    s.xs   = (float*)(sm + 32768);
    s.tnx  = (float*)(sm + 37888);
    s.hX   = (float*)(sm + 54400);
    s.idxl = (int*)(sm + 59520);
    s.adjr = (unsigned*)(sm + 59560);
    s.vmsk = (float*)(sm + 59600);
    s.df   = (float*)(sm + 59636);
    s.tns  = (float*)(sm + 60036);
    s.sc   = (float*)(sm + 61188);
    float* p = (float*)sm;
    s.hst = p;            p += 81;
    s.hsn = p;            p += 81;
    s.pbS = p;            p += 288;
    s.As  = p;            p += 288;
    s.Wsw = p;            p += 288;
    s.t1s = p;            p += 32;
    s.pbX = p;            p += 288;
    s.Ax  = p;            p += 288;
    s.Wxw = p;            p += 288;
    s.t1x = p;            p += 32;
    s.redA = p;           p += 256;
    s.redB = p;           p += 256;
    s.redC = p;           p += 256;
    s.dradA = p;          p += 64;
    s.hbv  = p;           p += 32;
    s.hpool = p;          p += 128;
    s.rbss = p;           p += 9;
    s.wrad = p;           p += 9;
    return s;
}

// lin + layernorm for 10 rows of 128; 256 threads; syncs internally.
__device__ __forceinline__ void lin_ln_10(const u16* Wl, const float* xs, float* h,
                                          const void* linb, const void* lng, const void* lnb,
                                          int t, int f32) {
    int d = t & 127, rh = t >> 7;
    float bias = ldv(linb, d, f32);
    for (int r = rh; r < 10; r += 2) {
        float acc = bias;
        const float* xr = xs + r * 128;
#pragma unroll 8
        for (int c = 0; c < 128; ++c)
            acc = fmaf(xr[c], bf2f(Wl[c * 128 + d]), acc);
        h[r * 128 + d] = acc;
    }
    __syncthreads();
    int lane = t & 63, w = t >> 6;
    float g0 = ldv(lng, lane, f32), g1 = ldv(lng, lane + 64, f32);
    float b0 = ldv(lnb, lane, f32), b1 = ldv(lnb, lane + 64, f32);
    for (int r = w; r < 10; r += 4) {
        float v0 = h[r * 128 + lane], v1 = h[r * 128 + 64 + lane];
        float s = v0 + v1, q = v0 * v0 + v1 * v1;
#pragma unroll
        for (int m = 32; m >= 1; m >>= 1) { s += __shfl_xor(s, m); q += __shfl_xor(q, m); }
        float mu = s * (1.f / 128.f);
        float var = fmaxf(q * (1.f / 128.f) - mu * mu, 0.f);
        float rs = rsqrtf(var + 1e-5f);
        h[r * 128 + lane]      = (v0 - mu) * rs * g0 + b0;
        h[r * 128 + 64 + lane] = (v1 - mu) * rs * g1 + b1;
    }
    __syncthreads();
}

// ---------------- kernel A: zero globals + normalize thetas ----------------
__global__ __launch_bounds__(256) void k_prep(const void* theta_x, const void* theta_s,
                                              const void* xlg) {
    int t = threadIdx.x;
    const int f32 = (((const u16*)xlg)[0] == 0);
    for (int i = t; i < LL * DX; i += 256) g_tnx[i] = 0.f;
    for (int i = t; i < LL * NN; i += 256) g_tns[i] = 0.f;
    for (int i = t; i < DX * KP; i += 256) g_hprt[i] = 0.f;
    for (int i = t; i < KP; i += 256) g_hprn[i] = 0.f;
    for (int i = t; i < 32 * KP; i += 256) g_hpt[i] = 0.f;
    for (int i = t; i < NN * KP; i += 256) g_rpst[i] = 0.f;
    for (int i = t; i < LL * NN * KP; i += 256) { g_ppxt[i] = 0; g_ppst[i] = 0; }
    __syncthreads();
    if (t < 32) {
        float s = 0;
        for (int d = 0; d < 128; d++) { float v = ldv(theta_x, t * 128 + d, f32); s = fmaf(v, v, s); }
        float inv = 1.f / sqrtf(s);
        for (int d = 0; d < 128; d++) g_tnx[t * 128 + d] = ldv(theta_x, t * 128 + d, f32) * inv;
    } else if (t < 64) {
        int l = t - 32;
        float s = 0;
        for (int j = 0; j < 9; j++) { float v = ldv(theta_s, l * 9 + j, f32); s = fmaf(v, v, s); }
        float inv = 1.f / sqrtf(s);
        for (int j = 0; j < 9; j++) g_tns[l * 9 + j] = ldv(theta_s, l * 9 + j, f32) * inv;
    }
}

// ---------------- kernel B: prototype-side precompute (64 blocks, 1 per k) ----------------
__global__ __launch_bounds__(256) void k_proto(
    const void* xlw, const void* xlb, const void* xlg, const void* xlbt,
    const void* slg, const void* slb, const void* wn_w1,
    const void* proto_root, const void* proto_neigh,
    const void* proto_rad, const void* proto_dn) {
    __shared__ __align__(16) unsigned char sm[61440];
    SMem S = make_smem(sm);
    int k = blockIdx.x, t = threadIdx.x;
    const int f32 = (((const u16*)xlg)[0] == 0);

    for (int i = t; i < 15360; i += 256) ((float*)sm)[i] = 0.f;   // zero-init all LDS
    __syncthreads();

    for (int i = t; i < 16384; i += 256)
        S.Wl[i] = f32 ? f2bf(((const float*)xlw)[i]) : ((const u16*)xlw)[i];
    for (int i = t; i < 4096; i += 256) { int l = i >> 7, d = i & 127; S.tnx[l * 129 + d] = g_tnx[i]; }
    for (int i = t; i < 288; i += 256) S.tns[i] = g_tns[i];
    {   // rows 0..8 = proto_neigh[k], row 9 = proto_root[k]
        int c = t & 127;
        for (int r = t >> 7; r < 10; r += 2) {
            S.xs[r * 128 + c] = (r < 9) ? ldv(proto_neigh, (k * 9 + r) * 128 + c, f32)
                                        : ldv(proto_root, k * 128 + c, f32);
        }
    }
    __syncthreads();
    lin_ln_10(S.Wl, S.xs, S.hX, xlb, xlg, xlbt, t, f32);

    if (t < 128) g_hprt[t * 64 + k] = S.hX[9 * 128 + t];
    if (t < 64) {
        float v0 = S.hX[9 * 128 + t], v1 = S.hX[9 * 128 + 64 + t];
        float q = v0 * v0 + v1 * v1;
#pragma unroll
        for (int m = 32; m >= 1; m >>= 1) q += __shfl_xor(q, m);
        if (t == 0) g_hprn[k] = q;
    }
    if (t < 32) {
        float acc = 0;
        for (int d = 0; d < 128; d++)
            acc = fmaf(S.hX[9 * 128 + d], ldv(wn_w1, (128 + d) * 32 + t, f32), acc);
        g_hpt[t * 64 + k] = acc;
    }
    {   // feature projections of proto neighbors
        int l = t & 31;
        for (int m = t >> 5; m < 9; m += 8) {
            float acc = 0;
            const float* hr = S.hX + m * 128; const float* tr = S.tnx + l * 129;
#pragma unroll 8
            for (int d = 0; d < 128; d++) acc = fmaf(hr[d], tr[d], acc);
            S.pbX[m * 32 + l] = acc;
        }
    }
    __syncthreads();
    if (t < 32) {
        float v[9]; int r[9];
#pragma unroll
        for (int m = 0; m < 9; m++) v[m] = S.pbX[m * 32 + t];
        rank9(v, r);
#pragma unroll
        for (int m = 0; m < 9; m++) g_ppxt[(t * 9 + r[m]) * 64 + k] = f2bf(v[m]);
    }
    // build C from proto_dn
    if (t < 81) {
        int i = t / 9, j = t % 9; float v = 0.f;
        if (i != j) {
            int a = (i < j) ? i : j, b = (i < j) ? j : i;
            int p = a * 8 - a * (a - 1) / 2 + (b - a - 1);   // triu_indices(9,1) row-major
            v = sigmoidf(ldv(proto_dn, p * 64 + k, f32));
        }
        S.hst[t] = v;
    }
    __syncthreads();
    if (t < 9) { // sort each column over rows
        float v[9]; int r[9];
#pragma unroll
        for (int i = 0; i < 9; i++) v[i] = S.hst[i * 9 + t];
        rank9(v, r);
#pragma unroll
        for (int i = 0; i < 9; i++) S.hst[r[i] * 9 + t] = v[i];
    }
    __syncthreads();
    if (t < 9) { // LN rows with s_ln
        float mu = 0;
#pragma unroll
        for (int j = 0; j < 9; j++) mu += S.hst[t * 9 + j];
        mu *= (1.f / 9.f);
        float var = 0;
#pragma unroll
        for (int j = 0; j < 9; j++) { float d0 = S.hst[t * 9 + j] - mu; var = fmaf(d0, d0, var); }
        var *= (1.f / 9.f);
        float rs = rsqrtf(var + 1e-5f);
#pragma unroll
        for (int j = 0; j < 9; j++)
            S.hsn[t * 9 + j] = (S.hst[t * 9 + j] - mu) * rs * ldv(slg, j, f32) + ldv(slb, j, f32);
    }
    __syncthreads();
    {
        int l = t & 31;
        for (int m = t >> 5; m < 9; m += 8) {
            float acc = 0;
#pragma unroll
            for (int j = 0; j < 9; j++) acc = fmaf(S.hsn[m * 9 + j], S.tns[l * 9 + j], acc);
            S.pbS[m * 32 + l] = acc;
        }
    }
    __syncthreads();
    if (t < 32) {
        float v[9]; int r[9];
#pragma unroll
        for (int m = 0; m < 9; m++) v[m] = S.pbS[m * 32 + t];
        rank9(v, r);
#pragma unroll
        for (int m = 0; m < 9; m++) g_ppst[(t * 9 + r[m]) * 64 + k] = f2bf(v[m]);
    }
    if (t == 0) {
        float v[9]; int r[9];
#pragma unroll
        for (int m = 0; m < 9; m++) v[m] = ldv(proto_rad, k * 9 + m, f32);
        rank9(v, r);
#pragma unroll
        for (int m = 0; m < 9; m++) g_rpst[r[m] * 64 + k] = v[m];
    }
}

// ---------------- main kernel: one block per batch element ----------------
__global__ __launch_bounds__(256) void k_main(
    const void* adj, const void* feat, const int* idxs,
    const void* xlw, const void* xlb, const void* xlg, const void* xlbt,
    const void* slg, const void* slb,
    const void* an_w1, const void* an_b1, const void* an_w2, const void* an_b2,
    const void* wn_w1, const void* wn_b1, const void* wn_w2, const void* wn_b2,
    const void* alpha_raw, const void* w_raw, const void* log_gamma,
    void* out) {
    __shared__ __align__(16) unsigned char sm[61440];
    SMem S = make_smem(sm);
    int b = blockIdx.x, t = threadIdx.x;
    const int f32 = (((const u16*)xlg)[0] == 0);

    for (int i = t; i < 15360; i += 256) ((float*)sm)[i] = 0.f;   // zero-init all LDS
    __syncthreads();

    // A1: stage loads
    for (int i = t; i < 16384; i += 256)
        S.Wl[i] = f32 ? f2bf(((const float*)xlw)[i]) : ((const u16*)xlw)[i];
    for (int i = t; i < 4096; i += 256) { int l = i >> 7, d = i & 127; S.tnx[l * 129 + d] = g_tnx[i]; }
    for (int i = t; i < 288; i += 256) S.tns[i] = g_tns[i];
    if (t < 10) S.idxl[t] = idxs[b * 10 + t];
    __syncthreads();
    // A2: mask, adjacency bits, gather
    if (t < 9) S.vmsk[t] = (S.idxl[t + 1] == NALL) ? 0.f : 1.f;
    if (t >= 16 && t < 26) {
        int i = t - 16; unsigned row = 0;
        for (int j = 0; j < 10; j++)
            if (ldv(adj, b * 100 + i * 10 + j, f32) > 1e-5f) row |= 1u << j;
        S.adjr[i] = row;
    }
    {
        int c = t & 127;
        for (int r = t >> 7; r < 10; r += 2) {
            int id = S.idxl[r];
            S.xs[r * 128 + c] = (id == NALL) ? 0.f : ldv(feat, id * 128 + c, f32);
        }
    }
    __syncthreads();
    // A3: lin + LN (root = row 0, neighbors = rows 1..9)
    lin_ln_10(S.Wl, S.xs, S.hX, xlb, xlg, xlbt, t, f32);
    // A4: BFS distances; ||h_root||^2
    if (t < 10) {
        unsigned row = S.adjr[t];
        int dl[10];
#pragma unroll
        for (int j = 0; j < 10; j++) dl[j] = (j == t) ? 0 : (((row >> j) & 1) ? 1 : 10);
        unsigned reach = row | (1u << t);
        for (int s = 2; s <= 9; s++) {
            unsigned nr = reach;
            for (int j = 0; j < 10; j++) if ((reach >> j) & 1) nr |= S.adjr[j];
            unsigned add = nr & ~reach;
            if (!add) break;
#pragma unroll
            for (int j = 0; j < 10; j++) if ((add >> j) & 1) dl[j] = s;
            reach = nr;
        }
        float mi = (t == 0) ? 1.f : S.vmsk[t - 1];
#pragma unroll
        for (int j = 0; j < 10; j++) {
            float mj = (j == 0) ? 1.f : S.vmsk[j - 1];
            S.df[t * 10 + j] = (mi > 0.f && mj > 0.f) ? (float)dl[j] * 0.1f : 1.0f;
        }
    }
    if (t >= 64 && t < 128) {
        int lane = t - 64;
        float v0 = S.hX[lane], v1 = S.hX[64 + lane];
        float q = v0 * v0 + v1 * v1;
#pragma unroll
        for (int m = 32; m >= 1; m >>= 1) q += __shfl_xor(q, m);
        if (lane == 0) S.sc[1] = q;
    }
    __syncthreads();
    // A5: radial sort (t0); structural column sort (t 64..72)
    if (t == 0) {
        float n = 0;
        for (int m = 0; m < 9; m++) n += S.vmsk[m];
        S.sc[0] = n + 1e-9f;
        float v[9]; int r[9];
#pragma unroll
        for (int m = 0; m < 9; m++) v[m] = S.df[1 + m];
        rank9(v, r);
#pragma unroll
        for (int m = 0; m < 9; m++) { S.rbss[r[m]] = v[m]; S.wrad[r[m]] = S.vmsk[m] / S.sc[0]; }
    }
    if (t >= 64 && t < 73) {
        int j = t - 64;
        float v[9]; int r[9];
#pragma unroll
        for (int i = 0; i < 9; i++) v[i] = S.df[(1 + i) * 10 + 1 + j];
        rank9(v, r);
#pragma unroll
        for (int i = 0; i < 9; i++) S.hst[r[i] * 9 + j] = v[i];
    }
    __syncthreads();
    // A6: LN rows of sorted structural matrix; pooled h
    if (t < 9) {
        float mu = 0;
#pragma unroll
        for (int j = 0; j < 9; j++) mu += S.hst[t * 9 + j];
        mu *= (1.f / 9.f);
        float var = 0;
#pragma unroll
        for (int j = 0; j < 9; j++) { float d0 = S.hst[t * 9 + j] - mu; var = fmaf(d0, d0, var); }
        var *= (1.f / 9.f);
        float rs = rsqrtf(var + 1e-5f);
#pragma unroll
        for (int j = 0; j < 9; j++)
            S.hsn[t * 9 + j] = (S.hst[t * 9 + j] - mu) * rs * ldv(slg, j, f32) + ldv(slb, j, f32);
    }
    if (t >= 64 && t < 192) {
        int d = t - 64;
        float a = 0;
#pragma unroll
        for (int m = 0; m < 9; m++) a = fmaf(S.hX[(1 + m) * 128 + d], S.vmsk[m], a);
        S.hpool[d] = a / S.sc[0];
    }
    __syncthreads();
    // A7: structural projections
    {
        int l = t & 31;
        for (int m = t >> 5; m < 9; m += 8) {
            float acc = 0;
#pragma unroll
            for (int j = 0; j < 9; j++) acc = fmaf(S.hsn[m * 9 + j], S.tns[l * 9 + j], acc);
            S.pbS[m * 32 + l] = acc;
        }
    }
    __syncthreads();
    // A8: structural per-l stable sort + weights; radial distances
    if (t < 32) {
        float v[9]; int r[9];
#pragma unroll
        for (int m = 0; m < 9; m++) v[m] = S.pbS[m * 32 + t];
        rank9(v, r);
        float t1 = 0;
#pragma unroll
        for (int m = 0; m < 9; m++) {
            float w = S.vmsk[m] / S.sc[0];
            S.As[t * 9 + r[m]] = w * v[m];
            S.Wsw[t * 9 + r[m]] = w;
            t1 = fmaf(w * v[m], v[m], t1);
        }
        S.t1s[t] = t1;
    }
    if (t >= 64 && t < 128) {
        int k = t - 64;
        float acc = 0;
#pragma unroll
        for (int m = 0; m < 9; m++) {
            float d0 = S.rbss[m] - g_rpst[m * 64 + k];
            acc = fmaf(d0 * d0, S.wrad[m], acc);
        }
        S.dradA[k] = acc;
    }
    __syncthreads();
    // A9: feature projections
    {
        int l = t & 31;
        for (int m = t >> 5; m < 9; m += 8) {
            float acc = 0;
            const float* hr = S.hX + (1 + m) * 128; const float* tr = S.tnx + l * 129;
#pragma unroll 8
            for (int d = 0; d < 128; d++) acc = fmaf(hr[d], tr[d], acc);
            S.pbX[m * 32 + l] = acc;
        }
    }
    __syncthreads();
    // A10: feature per-l sort; hb partials; alpha MLP partials
    if (t < 32) {
        float v[9]; int r[9];
#pragma unroll
        for (int m = 0; m < 9; m++) v[m] = S.pbX[m * 32 + t];
        rank9(v, r);
        float t1 = 0;
#pragma unroll
        for (int m = 0; m < 9; m++) {
            float w = S.vmsk[m] / S.sc[0];
            S.Ax[t * 9 + r[m]] = w * v[m];
            S.Wxw[t * 9 + r[m]] = w;
            t1 = fmaf(w * v[m], v[m], t1);
        }
        S.t1x[t] = t1;
    }
    if (t >= 64 && t < 192) {
        int t2 = t - 64; int j = t2 & 31, dg = t2 >> 5;
        float acc = 0;
        for (int d = dg * 32; d < dg * 32 + 32; d++)
            acc = fmaf(S.hX[d], ldv(wn_w1, d * 32 + j, f32), acc);
        S.redA[t2] = acc;
    }
    if (t >= 192 && t < 224) {
        int j = t - 192;
        float acc = ldv(an_b1, j, f32);
#pragma unroll 8
        for (int d = 0; d < 128; d++)
            acc = fmaf(S.hpool[d], ldv(an_w1, d * 32 + j, f32), acc);
        acc = fmaxf(acc, 0.f);
        S.redB[j] = acc * ldv(an_w2, j, f32);
    }
    __syncthreads();
    // A11: combine hb; alpha scalar
    if (t < 32) S.hbv[t] = S.redA[t] + S.redA[32 + t] + S.redA[64 + t] + S.redA[96 + t] + ldv(wn_b1, t, f32);
    if (t == 32) {
        float s = 0;
        for (int j = 0; j < 32; j++) s += S.redB[j];
        s += ldv(an_b2, 0, f32);
        S.sc[2] = sigmoidf(ldv(alpha_raw, 0, f32) + s);
    }
    __syncthreads();
    // A12: k-loop partials (sw_feat, sw_str, root-feat dot)
    {
        int k = t & 63, lg = t >> 6;
        float af = 0, as_ = 0;
        for (int l = lg * 8; l < lg * 8 + 8; l++) {
            af += S.t1x[l]; as_ += S.t1s[l];
#pragma unroll
            for (int m = 0; m < 9; m++) {
                float pf = bf2f(g_ppxt[(l * 9 + m) * 64 + k]);
                af += pf * (S.Wxw[l * 9 + m] * pf - 2.f * S.Ax[l * 9 + m]);
                float qf = bf2f(g_ppst[(l * 9 + m) * 64 + k]);
                as_ += qf * (S.Wsw[l * 9 + m] * qf - 2.f * S.As[l * 9 + m]);
            }
        }
        S.redA[t] = af; S.redB[t] = as_;
        float dot = 0;
        for (int d = lg * 32; d < lg * 32 + 32; d++)
            dot = fmaf(S.hX[d], g_hprt[d * 64 + k], dot);
        S.redC[t] = dot;
    }
    __syncthreads();
    // A13: finalize per k
    if (t < 64) {
        int k = t;
        float swfk = (S.redA[k] + S.redA[64 + k] + S.redA[128 + k] + S.redA[192 + k]) * (1.f / 32.f);
        float swsk = (S.redB[k] + S.redB[64 + k] + S.redB[128 + k] + S.redB[192 + k]) * (1.f / 32.f);
        float dot  = S.redC[k] + S.redC[64 + k] + S.redC[128 + k] + S.redC[192 + k];
        float drfk = S.sc[1] + g_hprn[k] - 2.f * dot;
        float wl = 0;
        for (int j = 0; j < 32; j++) {
            float vv = S.hbv[j] + g_hpt[j * 64 + k];
            wl = fmaf(fmaxf(vv, 0.f), ldv(wn_w2, j, f32), wl);
        }
        wl += ldv(wn_b2, 0, f32);
        float w = sigmoidf(ldv(w_raw, 0, f32) + wl);
        float dfeat = w * drfk + (1.f - w) * swfk;
        float dstr  = w * S.dradA[k] + (1.f - w) * swsk;
        float al = S.sc[2];
        float dfgw = al * dfeat + (1.f - al) * dstr;
        if (!(dfgw == dfgw)) dfgw = 1e30f;   // NaN diagnostic guard -> out 0
        float gamma = expf(ldv(log_gamma, 0, f32));
        float res = expf(-gamma * dfgw);
        // output dtype follows the harness's uniform dtype convention
        if (f32) ((float*)out)[b * 64 + k] = res;
        else     ((u16*)out)[b * 64 + k] = f2bf(res);
    }
}

extern "C" void kernel_launch(void* const* d_in, const int* in_sizes, int n_in,
                              void* d_out, int out_size, void* d_ws, size_t ws_size,
                              hipStream_t stream) {
    const void* adj  = d_in[0];
    const void* feat = d_in[1];
    const int*  idxs = (const int*)d_in[2];
    const void* xlw  = d_in[3];
    const void* xlb  = d_in[4];
    const void* xlg  = d_in[5];
    const void* xlbt = d_in[6];
    const void* slg  = d_in[7];
    const void* slb  = d_in[8];
    const void* thx  = d_in[9];
    const void* ths  = d_in[10];
    const void* araw = d_in[11];
    const void* anw1 = d_in[12];
    const void* anb1 = d_in[13];
    const void* anw2 = d_in[14];
    const void* anb2 = d_in[15];
    const void* wnw1 = d_in[16];
    const void* wnb1 = d_in[17];
    const void* wnw2 = d_in[18];
    const void* wnb2 = d_in[19];
    const void* wraw = d_in[20];
    const void* prt  = d_in[21];
    const void* prn  = d_in[22];
    const void* prad = d_in[23];
    const void* pdn  = d_in[24];
    const void* lgam = d_in[25];
    int B = in_sizes[2] / 10;

    k_prep<<<1, 256, 0, stream>>>(thx, ths, xlg);
    k_proto<<<64, 256, 0, stream>>>(xlw, xlb, xlg, xlbt, slg, slb, wnw1,
                                    prt, prn, prad, pdn);
    k_main<<<B, 256, 0, stream>>>(adj, feat, idxs, xlw, xlb, xlg, xlbt, slg, slb,
                                  anw1, anb1, anw2, anb2, wnw1, wnb1, wnw2, wnb2,
                                  araw, wraw, lgam, d_out);
}

// Round 5
// 568.081 us; speedup vs baseline: 1.6348x; 1.6348x over previous
//
#include <hip/hip_runtime.h>
#include <hip/hip_bf16.h>

typedef unsigned short u16;

#define NN 9
#define DX 128
#define KP 64
#define LL 32
#define NALL 100000
#define BMAX 8192
#define NB 4

// ---------- cross-kernel tables as typed device globals ----------
__device__ __align__(16) float g_tnx[LL * DX];       // normalized theta_x [l][d] (k_proto use)
__device__ __align__(16) float g_tnxT[DX * LL];      // normalized theta_x transposed [d][l] (k_main use)
__device__ __align__(16) float g_tns[LL * NN];       // normalized theta_s [l][j]
__device__ __align__(16) float g_hprt[DX * KP];      // h_proto_root^T [d][k]
__device__ __align__(16) float g_hprn[KP];           // ||h_proto_root||^2 [k]
__device__ __align__(16) float g_hpt[32 * KP];       // hp^T [j][k]
__device__ __align__(16) float g_rpst[NN * KP];      // sorted proto_rad [m][k]
__device__ __align__(16) u16   g_ppxt[LL * NN * KP]; // sorted proto proj (feat) bf16 [(l*9+m)][k]
__device__ __align__(16) u16   g_ppst[LL * NN * KP]; // sorted proto proj (str)  bf16
__device__ __align__(16) u16   g_hx[BMAX * 10 * DX]; // LN'd h rows, bf16

__device__ __forceinline__ float bf2f(u16 u) {
    union { unsigned u; float f; } v; v.u = ((unsigned)u) << 16; return v.f;
}
__device__ __forceinline__ u16 f2bf(float f) {
    __hip_bfloat16 h = __float2bfloat16(f);
    union { __hip_bfloat16 h; u16 u; } v; v.h = h; return v.u;
}
// dtype-robust load: f32!=0 -> buffer is float32, else bf16
__device__ __forceinline__ float ldv(const void* p, int i, int f32) {
    return f32 ? ((const float*)p)[i] : bf2f(((const u16*)p)[i]);
}
__device__ __forceinline__ float sigmoidf(float x) { return 1.f / (1.f + expf(-x)); }

// branch-free stable rank of 9 values (tie -> lower original index first)
__device__ __forceinline__ void rank9(const float* v, int* r) {
#pragma unroll
    for (int m = 0; m < 9; m++) {
        int rk = 0;
#pragma unroll
        for (int n = 0; n < 9; n++)
            rk += (v[n] < v[m]) || (v[n] == v[m] && n < m);
        r[m] = rk;
    }
}

// ---------------- kernel A: zero tables + normalize thetas ----------------
__global__ __launch_bounds__(256) void k_prep(const void* theta_x, const void* theta_s,
                                              const void* xlg) {
    int t = threadIdx.x;
    const int f32 = (((const u16*)xlg)[0] == 0);
    if (t < 32) {
        float s = 0;
        for (int d = 0; d < 128; d++) { float v = ldv(theta_x, t * 128 + d, f32); s = fmaf(v, v, s); }
        float inv = 1.f / sqrtf(s);
        for (int d = 0; d < 128; d++) {
            float v = ldv(theta_x, t * 128 + d, f32) * inv;
            g_tnx[t * 128 + d] = v;
            g_tnxT[d * 32 + t] = v;
        }
    } else if (t < 64) {
        int l = t - 32;
        float s = 0;
        for (int j = 0; j < 9; j++) { float v = ldv(theta_s, l * 9 + j, f32); s = fmaf(v, v, s); }
        float inv = 1.f / sqrtf(s);
        for (int j = 0; j < 9; j++) g_tns[l * 9 + j] = ldv(theta_s, l * 9 + j, f32) * inv;
    }
}

// ---------------- kernel L: linear + LN for all (b, row) ----------------
// W column d lives in VGPRs (packed bf16 pairs); x rows in lane registers,
// broadcast via v_readlane (VALU pipe, no LDS-pipe contention).
__global__ __launch_bounds__(256) void k_lin(const void* feat, const int* idxs,
                                             const void* xlw, const void* xlb,
                                             const void* xlg, const void* xlbt, int B) {
    __shared__ float hsh[1280];
    int t = threadIdx.x;
    const int f32 = (((const u16*)xlg)[0] == 0);
    int d = t & 127, rh = t >> 7, lane = t & 63, w = t >> 6;

    unsigned wreg[64];
#pragma unroll
    for (int i = 0; i < 64; i++) {
        float w0 = ldv(xlw, (2 * i) * 128 + d, f32);
        float w1 = ldv(xlw, (2 * i + 1) * 128 + d, f32);
        wreg[i] = (unsigned)f2bf(w0) | (((unsigned)f2bf(w1)) << 16);
    }
    float bias = ldv(xlb, d, f32);
    float g0 = ldv(xlg, lane, f32), g1 = ldv(xlg, lane + 64, f32);
    float b0 = ldv(xlbt, lane, f32), b1 = ldv(xlbt, lane + 64, f32);

    for (int bi = 0; bi < NB; bi++) {
        int b = blockIdx.x * NB + bi;
        if (b >= B) break;
        float xr[5][2];
#pragma unroll
        for (int q = 0; q < 5; q++) {
            int r = rh + 2 * q;
            int id = idxs[b * 10 + r];
            if (id == NALL) { xr[q][0] = 0.f; xr[q][1] = 0.f; }
            else {
                xr[q][0] = ldv(feat, id * 128 + lane, f32);
                xr[q][1] = ldv(feat, id * 128 + 64 + lane, f32);
            }
        }
        float acc[5];
#pragma unroll
        for (int q = 0; q < 5; q++) acc[q] = bias;
#pragma unroll
        for (int c = 0; c < 128; c++) {
            unsigned wp = wreg[c >> 1];
            float wv = (c & 1) ? __uint_as_float(wp & 0xffff0000u)
                               : __uint_as_float(wp << 16);
#pragma unroll
            for (int q = 0; q < 5; q++) {
                int xv = __builtin_amdgcn_readlane(__float_as_int(xr[q][c >> 6]), c & 63);
                acc[q] = fmaf(__int_as_float(xv), wv, acc[q]);
            }
        }
#pragma unroll
        for (int q = 0; q < 5; q++) hsh[(rh + 2 * q) * 128 + d] = acc[q];
        __syncthreads();
        for (int r = w; r < 10; r += 4) {
            float v0 = hsh[r * 128 + lane], v1 = hsh[r * 128 + 64 + lane];
            float s = v0 + v1, q = v0 * v0 + v1 * v1;
#pragma unroll
            for (int m = 32; m >= 1; m >>= 1) { s += __shfl_xor(s, m); q += __shfl_xor(q, m); }
            float mu = s * (1.f / 128.f);
            float var = fmaxf(q * (1.f / 128.f) - mu * mu, 0.f);
            float rs = rsqrtf(var + 1e-5f);
            g_hx[(b * 10 + r) * 128 + lane]      = f2bf((v0 - mu) * rs * g0 + b0);
            g_hx[(b * 10 + r) * 128 + 64 + lane] = f2bf((v1 - mu) * rs * g1 + b1);
        }
        __syncthreads();
    }
}

// ---------------- kernel B: prototype-side precompute (64 blocks, 1 per k) ----------------
// (unchanged structure from round 4; small & off the critical path)
struct PSMem {
    u16   Wl[16384];
    float xs[1280];
    float tnx[LL * 129];
    float hX[1280];
    float tns[288];
    float hst[81], hsn[81], pbS[288], pbX[288];
};
__global__ __launch_bounds__(256) void k_proto(
    const void* xlw, const void* xlb, const void* xlg, const void* xlbt,
    const void* slg, const void* slb, const void* wn_w1,
    const void* proto_root, const void* proto_neigh,
    const void* proto_rad, const void* proto_dn) {
    __shared__ PSMem S;
    int k = blockIdx.x, t = threadIdx.x;
    const int f32 = (((const u16*)xlg)[0] == 0);

    for (int i = t; i < 16384; i += 256)
        S.Wl[i] = f32 ? f2bf(((const float*)xlw)[i]) : ((const u16*)xlw)[i];
    for (int i = t; i < 4096; i += 256) { int l = i >> 7, d = i & 127; S.tnx[l * 129 + d] = g_tnx[i]; }
    for (int i = t; i < 288; i += 256) S.tns[i] = g_tns[i];
    {
        int c = t & 127;
        for (int r = t >> 7; r < 10; r += 2)
            S.xs[r * 128 + c] = (r < 9) ? ldv(proto_neigh, (k * 9 + r) * 128 + c, f32)
                                        : ldv(proto_root, k * 128 + c, f32);
    }
    __syncthreads();
    {   // lin
        int d = t & 127, rh = t >> 7;
        float bias = ldv(xlb, d, f32);
        for (int r = rh; r < 10; r += 2) {
            float acc = bias;
            const float* xr2 = S.xs + r * 128;
#pragma unroll 8
            for (int c = 0; c < 128; ++c)
                acc = fmaf(xr2[c], bf2f(S.Wl[c * 128 + d]), acc);
            S.hX[r * 128 + d] = acc;
        }
    }
    __syncthreads();
    {   // LN
        int lane = t & 63, w = t >> 6;
        float g0 = ldv(xlg, lane, f32), g1 = ldv(xlg, lane + 64, f32);
        float b0 = ldv(xlbt, lane, f32), b1 = ldv(xlbt, lane + 64, f32);
        for (int r = w; r < 10; r += 4) {
            float v0 = S.hX[r * 128 + lane], v1 = S.hX[r * 128 + 64 + lane];
            float s = v0 + v1, q = v0 * v0 + v1 * v1;
#pragma unroll
            for (int m = 32; m >= 1; m >>= 1) { s += __shfl_xor(s, m); q += __shfl_xor(q, m); }
            float mu = s * (1.f / 128.f);
            float var = fmaxf(q * (1.f / 128.f) - mu * mu, 0.f);
            float rs = rsqrtf(var + 1e-5f);
            S.hX[r * 128 + lane]      = (v0 - mu) * rs * g0 + b0;
            S.hX[r * 128 + 64 + lane] = (v1 - mu) * rs * g1 + b1;
        }
    }
    __syncthreads();

    if (t < 128) g_hprt[t * 64 + k] = S.hX[9 * 128 + t];
    if (t < 64) {
        float v0 = S.hX[9 * 128 + t], v1 = S.hX[9 * 128 + 64 + t];
        float q = v0 * v0 + v1 * v1;
#pragma unroll
        for (int m = 32; m >= 1; m >>= 1) q += __shfl_xor(q, m);
        if (t == 0) g_hprn[k] = q;
    }
    if (t < 32) {
        float acc = 0;
        for (int d = 0; d < 128; d++)
            acc = fmaf(S.hX[9 * 128 + d], ldv(wn_w1, (128 + d) * 32 + t, f32), acc);
        g_hpt[t * 64 + k] = acc;
    }
    {
        int l = t & 31;
        for (int m = t >> 5; m < 9; m += 8) {
            float acc = 0;
            const float* hr = S.hX + m * 128; const float* tr = S.tnx + l * 129;
#pragma unroll 8
            for (int d = 0; d < 128; d++) acc = fmaf(hr[d], tr[d], acc);
            S.pbX[m * 32 + l] = acc;
        }
    }
    __syncthreads();
    if (t < 32) {
        float v[9]; int r[9];
#pragma unroll
        for (int m = 0; m < 9; m++) v[m] = S.pbX[m * 32 + t];
        rank9(v, r);
#pragma unroll
        for (int m = 0; m < 9; m++) g_ppxt[(t * 9 + r[m]) * 64 + k] = f2bf(v[m]);
    }
    if (t < 81) {
        int i = t / 9, j = t % 9; float v = 0.f;
        if (i != j) {
            int a = (i < j) ? i : j, b = (i < j) ? j : i;
            int p = a * 8 - a * (a - 1) / 2 + (b - a - 1);
            v = sigmoidf(ldv(proto_dn, p * 64 + k, f32));
        }
        S.hst[t] = v;
    }
    __syncthreads();
    if (t < 9) {
        float v[9]; int r[9];
#pragma unroll
        for (int i = 0; i < 9; i++) v[i] = S.hst[i * 9 + t];
        rank9(v, r);
#pragma unroll
        for (int i = 0; i < 9; i++) S.hst[r[i] * 9 + t] = v[i];
    }
    __syncthreads();
    if (t < 9) {
        float mu = 0;
#pragma unroll
        for (int j = 0; j < 9; j++) mu += S.hst[t * 9 + j];
        mu *= (1.f / 9.f);
        float var = 0;
#pragma unroll
        for (int j = 0; j < 9; j++) { float d0 = S.hst[t * 9 + j] - mu; var = fmaf(d0, d0, var); }
        var *= (1.f / 9.f);
        float rs = rsqrtf(var + 1e-5f);
#pragma unroll
        for (int j = 0; j < 9; j++)
            S.hsn[t * 9 + j] = (S.hst[t * 9 + j] - mu) * rs * ldv(slg, j, f32) + ldv(slb, j, f32);
    }
    __syncthreads();
    {
        int l = t & 31;
        for (int m = t >> 5; m < 9; m += 8) {
            float acc = 0;
#pragma unroll
            for (int j = 0; j < 9; j++) acc = fmaf(S.hsn[m * 9 + j], S.tns[l * 9 + j], acc);
            S.pbS[m * 32 + l] = acc;
        }
    }
    __syncthreads();
    if (t < 32) {
        float v[9]; int r[9];
#pragma unroll
        for (int m = 0; m < 9; m++) v[m] = S.pbS[m * 32 + t];
        rank9(v, r);
#pragma unroll
        for (int m = 0; m < 9; m++) g_ppst[(t * 9 + r[m]) * 64 + k] = f2bf(v[m]);
    }
    if (t == 0) {
        float v[9]; int r[9];
#pragma unroll
        for (int m = 0; m < 9; m++) v[m] = ldv(proto_rad, k * 9 + m, f32);
        rank9(v, r);
#pragma unroll
        for (int m = 0; m < 9; m++) g_rpst[r[m] * 64 + k] = v[m];
    }
}

// ---------------- main kernel: one block per batch element ----------------
struct MSMem {
    float hX[1280];
    float tns[288];
    float hst[81], hsn[81];
    float pbS[288], As[288], Wsw[288], t1s[32];
    float pbX[288], Ax[288], Wxw[288], t1x[32];
    float redA[256], redB[256], redC[256];
    float dradA[64], hbv[32], hpool[128], rbss[9], wrad[9];
    float vmsk[9], df[100], sc[4];
    int idxl[10]; unsigned adjr[10];
};
__global__ __launch_bounds__(256) void k_main(
    const void* adj, const int* idxs,
    const void* slg, const void* slb,
    const void* an_w1, const void* an_b1, const void* an_w2, const void* an_b2,
    const void* wn_w1, const void* wn_b1, const void* wn_w2, const void* wn_b2,
    const void* alpha_raw, const void* w_raw, const void* log_gamma,
    const void* xlg, void* out) {
    __shared__ MSMem S;
    int b = blockIdx.x, t = threadIdx.x;
    const int f32 = (((const u16*)xlg)[0] == 0);

    // P1: stage hX (bf16 -> f32), tns, idxl
    for (int i = t; i < 1280; i += 256) S.hX[i] = bf2f(g_hx[b * 1280 + i]);
    for (int i = t; i < 288; i += 256) S.tns[i] = g_tns[i];
    if (t < 10) S.idxl[t] = idxs[b * 10 + t];
    __syncthreads();
    // P2: vmask, adjacency bits, ||h_root||^2
    if (t < 9) S.vmsk[t] = (S.idxl[t + 1] == NALL) ? 0.f : 1.f;
    if (t >= 16 && t < 26) {
        int i = t - 16; unsigned row = 0;
        for (int j = 0; j < 10; j++)
            if (ldv(adj, b * 100 + i * 10 + j, f32) > 1e-5f) row |= 1u << j;
        S.adjr[i] = row;
    }
    if (t >= 64 && t < 128) {
        int lane = t - 64;
        float v0 = S.hX[lane], v1 = S.hX[64 + lane];
        float q = v0 * v0 + v1 * v1;
#pragma unroll
        for (int m = 32; m >= 1; m >>= 1) q += __shfl_xor(q, m);
        if (lane == 0) S.sc[1] = q;
    }
    __syncthreads();
    // P3: BFS distances
    if (t < 10) {
        unsigned row = S.adjr[t];
        int dl[10];
#pragma unroll
        for (int j = 0; j < 10; j++) dl[j] = (j == t) ? 0 : (((row >> j) & 1) ? 1 : 10);
        unsigned reach = row | (1u << t);
        for (int s = 2; s <= 9; s++) {
            unsigned nr = reach;
            for (int j = 0; j < 10; j++) if ((reach >> j) & 1) nr |= S.adjr[j];
            unsigned add = nr & ~reach;
            if (!add) break;
#pragma unroll
            for (int j = 0; j < 10; j++) if ((add >> j) & 1) dl[j] = s;
            reach = nr;
        }
        float mi = (t == 0) ? 1.f : S.vmsk[t - 1];
#pragma unroll
        for (int j = 0; j < 10; j++) {
            float mj = (j == 0) ? 1.f : S.vmsk[j - 1];
            S.df[t * 10 + j] = (mi > 0.f && mj > 0.f) ? (float)dl[j] * 0.1f : 1.0f;
        }
    }
    __syncthreads();
    // P4: n, radial sort (t0); structural column sort (t64..72)
    if (t == 0) {
        float n = 0;
        for (int m = 0; m < 9; m++) n += S.vmsk[m];
        S.sc[0] = n + 1e-9f;
        float v[9]; int r[9];
#pragma unroll
        for (int m = 0; m < 9; m++) v[m] = S.df[1 + m];
        rank9(v, r);
#pragma unroll
        for (int m = 0; m < 9; m++) { S.rbss[r[m]] = v[m]; S.wrad[r[m]] = S.vmsk[m] / S.sc[0]; }
    }
    if (t >= 64 && t < 73) {
        int j = t - 64;
        float v[9]; int r[9];
#pragma unroll
        for (int i = 0; i < 9; i++) v[i] = S.df[(1 + i) * 10 + 1 + j];
        rank9(v, r);
#pragma unroll
        for (int i = 0; i < 9; i++) S.hst[r[i] * 9 + j] = v[i];
    }
    __syncthreads();
    // P5: LN rows of sorted structural matrix; pooled h
    if (t < 9) {
        float mu = 0;
#pragma unroll
        for (int j = 0; j < 9; j++) mu += S.hst[t * 9 + j];
        mu *= (1.f / 9.f);
        float var = 0;
#pragma unroll
        for (int j = 0; j < 9; j++) { float d0 = S.hst[t * 9 + j] - mu; var = fmaf(d0, d0, var); }
        var *= (1.f / 9.f);
        float rs = rsqrtf(var + 1e-5f);
#pragma unroll
        for (int j = 0; j < 9; j++)
            S.hsn[t * 9 + j] = (S.hst[t * 9 + j] - mu) * rs * ldv(slg, j, f32) + ldv(slb, j, f32);
    }
    if (t >= 64 && t < 192) {
        int d = t - 64;
        float a = 0;
#pragma unroll
        for (int m = 0; m < 9; m++) a = fmaf(S.hX[(1 + m) * 128 + d], S.vmsk[m], a);
        S.hpool[d] = a / S.sc[0];
    }
    __syncthreads();
    // P6: structural projections
    {
        int l = t & 31;
        for (int m = t >> 5; m < 9; m += 8) {
            float acc = 0;
#pragma unroll
            for (int j = 0; j < 9; j++) acc = fmaf(S.hsn[m * 9 + j], S.tns[l * 9 + j], acc);
            S.pbS[m * 32 + l] = acc;
        }
    }
    __syncthreads();
    // P7: structural per-l stable sort + weights; radial distances
    if (t < 32) {
        float v[9]; int r[9];
#pragma unroll
        for (int m = 0; m < 9; m++) v[m] = S.pbS[m * 32 + t];
        rank9(v, r);
        float t1 = 0;
#pragma unroll
        for (int m = 0; m < 9; m++) {
            float w = S.vmsk[m] / S.sc[0];
            S.As[t * 9 + r[m]] = w * v[m];
            S.Wsw[t * 9 + r[m]] = w;
            t1 = fmaf(w * v[m], v[m], t1);
        }
        S.t1s[t] = t1;
    }
    if (t >= 64 && t < 128) {
        int k = t - 64;
        float acc = 0;
#pragma unroll
        for (int m = 0; m < 9; m++) {
            float d0 = S.rbss[m] - g_rpst[m * 64 + k];
            acc = fmaf(d0 * d0, S.wrad[m], acc);
        }
        S.dradA[k] = acc;
    }
    __syncthreads();
    // P8: feature projections (theta_x transposed, coalesced L1-hot)
    {
        int l = t & 31;
        for (int m = t >> 5; m < 9; m += 8) {
            float acc = 0;
            const float* hr = S.hX + (1 + m) * 128;
#pragma unroll 4
            for (int d = 0; d < 128; d++)
                acc = fmaf(hr[d], g_tnxT[d * 32 + l], acc);
            S.pbX[m * 32 + l] = acc;
        }
    }
    __syncthreads();
    // P9: feature per-l sort; hb partials; alpha MLP partials
    if (t < 32) {
        float v[9]; int r[9];
#pragma unroll
        for (int m = 0; m < 9; m++) v[m] = S.pbX[m * 32 + t];
        rank9(v, r);
        float t1 = 0;
#pragma unroll
        for (int m = 0; m < 9; m++) {
            float w = S.vmsk[m] / S.sc[0];
            S.Ax[t * 9 + r[m]] = w * v[m];
            S.Wxw[t * 9 + r[m]] = w;
            t1 = fmaf(w * v[m], v[m], t1);
        }
        S.t1x[t] = t1;
    }
    if (t >= 64 && t < 192) {
        int t2 = t - 64; int j = t2 & 31, dg = t2 >> 5;
        float acc = 0;
        for (int d = dg * 32; d < dg * 32 + 32; d++)
            acc = fmaf(S.hX[d], ldv(wn_w1, d * 32 + j, f32), acc);
        S.redA[t2] = acc;
    }
    if (t >= 192 && t < 224) {
        int j = t - 192;
        float acc = ldv(an_b1, j, f32);
#pragma unroll 8
        for (int d = 0; d < 128; d++)
            acc = fmaf(S.hpool[d], ldv(an_w1, d * 32 + j, f32), acc);
        acc = fmaxf(acc, 0.f);
        S.redB[j] = acc * ldv(an_w2, j, f32);
    }
    __syncthreads();
    // P10: combine hb; alpha scalar
    if (t < 32) S.hbv[t] = S.redA[t] + S.redA[32 + t] + S.redA[64 + t] + S.redA[96 + t] + ldv(wn_b1, t, f32);
    if (t == 32) {
        float s = 0;
        for (int j = 0; j < 32; j++) s += S.redB[j];
        s += ldv(an_b2, 0, f32);
        S.sc[2] = sigmoidf(ldv(alpha_raw, 0, f32) + s);
    }
    __syncthreads();
    // P11: k-loop partials (sw_feat, sw_str, root-feat dot)
    {
        int k = t & 63, lg = t >> 6;
        float af = 0, as_ = 0;
        for (int l = lg * 8; l < lg * 8 + 8; l++) {
            af += S.t1x[l]; as_ += S.t1s[l];
#pragma unroll
            for (int m = 0; m < 9; m++) {
                float pf = bf2f(g_ppxt[(l * 9 + m) * 64 + k]);
                af += pf * (S.Wxw[l * 9 + m] * pf - 2.f * S.Ax[l * 9 + m]);
                float qf = bf2f(g_ppst[(l * 9 + m) * 64 + k]);
                as_ += qf * (S.Wsw[l * 9 + m] * qf - 2.f * S.As[l * 9 + m]);
            }
        }
        S.redA[t] = af; S.redB[t] = as_;
        float dot = 0;
        for (int d = lg * 32; d < lg * 32 + 32; d++)
            dot = fmaf(S.hX[d], g_hprt[d * 64 + k], dot);
        S.redC[t] = dot;
    }
    __syncthreads();
    // P12: finalize per k
    if (t < 64) {
        int k = t;
        float swfk = (S.redA[k] + S.redA[64 + k] + S.redA[128 + k] + S.redA[192 + k]) * (1.f / 32.f);
        float swsk = (S.redB[k] + S.redB[64 + k] + S.redB[128 + k] + S.redB[192 + k]) * (1.f / 32.f);
        float dot  = S.redC[k] + S.redC[64 + k] + S.redC[128 + k] + S.redC[192 + k];
        float drfk = S.sc[1] + g_hprn[k] - 2.f * dot;
        float wl = 0;
        for (int j = 0; j < 32; j++) {
            float vv = S.hbv[j] + g_hpt[j * 64 + k];
            wl = fmaf(fmaxf(vv, 0.f), ldv(wn_w2, j, f32), wl);
        }
        wl += ldv(wn_b2, 0, f32);
        float w = sigmoidf(ldv(w_raw, 0, f32) + wl);
        float dfeat = w * drfk + (1.f - w) * swfk;
        float dstr  = w * S.dradA[k] + (1.f - w) * swsk;
        float al = S.sc[2];
        float dfgw = al * dfeat + (1.f - al) * dstr;
        if (!(dfgw == dfgw)) dfgw = 1e30f;
        float gamma = expf(ldv(log_gamma, 0, f32));
        float res = expf(-gamma * dfgw);
        if (f32) ((float*)out)[b * 64 + k] = res;
        else     ((u16*)out)[b * 64 + k] = f2bf(res);
    }
}

extern "C" void kernel_launch(void* const* d_in, const int* in_sizes, int n_in,
                              void* d_out, int out_size, void* d_ws, size_t ws_size,
                              hipStream_t stream) {
    const void* adj  = d_in[0];
    const void* feat = d_in[1];
    const int*  idxs = (const int*)d_in[2];
    const void* xlw  = d_in[3];
    const void* xlb  = d_in[4];
    const void* xlg  = d_in[5];
    const void* xlbt = d_in[6];
    const void* slg  = d_in[7];
    const void* slb  = d_in[8];
    const void* thx  = d_in[9];
    const void* ths  = d_in[10];
    const void* araw = d_in[11];
    const void* anw1 = d_in[12];
    const void* anb1 = d_in[13];
    const void* anw2 = d_in[14];
    const void* anb2 = d_in[15];
    const void* wnw1 = d_in[16];
    const void* wnb1 = d_in[17];
    const void* wnw2 = d_in[18];
    const void* wnb2 = d_in[19];
    const void* wraw = d_in[20];
    const void* prt  = d_in[21];
    const void* prn  = d_in[22];
    const void* prad = d_in[23];
    const void* pdn  = d_in[24];
    const void* lgam = d_in[25];
    int B = in_sizes[2] / 10;

    k_prep<<<1, 256, 0, stream>>>(thx, ths, xlg);
    k_lin<<<(B + NB - 1) / NB, 256, 0, stream>>>(feat, idxs, xlw, xlb, xlg, xlbt, B);
    k_proto<<<64, 256, 0, stream>>>(xlw, xlb, xlg, xlbt, slg, slb, wnw1,
                                    prt, prn, prad, pdn);
    k_main<<<B, 256, 0, stream>>>(adj, idxs, slg, slb,
                                  anw1, anb1, anw2, anb2, wnw1, wnb1, wnw2, wnb2,
                                  araw, wraw, lgam, xlg, d_out);
}

// Round 6
// 425.121 us; speedup vs baseline: 2.1845x; 1.3363x over previous
//
#include <hip/hip_runtime.h>
#include <hip/hip_bf16.h>

typedef unsigned short u16;
typedef __attribute__((ext_vector_type(8))) short short8;   // 8 bf16 (4 VGPRs)
typedef __attribute__((ext_vector_type(4))) float f32x4;

#define NN 9
#define DX 128
#define KP 64
#define LL 32
#define NALL 100000
#define BMAX 8192
#define NB 4

#define MFMA(a, b, c) __builtin_amdgcn_mfma_f32_16x16x32_bf16(a, b, c, 0, 0, 0)

// ---------- cross-kernel tables as typed device globals ----------
__device__ __align__(16) float g_tnx[LL * DX];        // normalized theta_x [l][d] (k_proto)
__device__ __align__(16) float g_tns[LL * NN];        // normalized theta_s [l][j]
__device__ __align__(16) float g_hprn[KP];            // ||h_proto_root||^2 [k]
__device__ __align__(16) float g_hpt[32 * KP];        // hp^T [j][k]
__device__ __align__(16) float g_rpst[NN * KP];       // sorted proto_rad [m][k]
__device__ __align__(16) u16   g_hx[BMAX * 10 * DX];  // LN'd h rows, bf16
// MFMA fragment-packed B tables (bf16)
__device__ __align__(16) u16   g_pBt[4096];           // proj B: tnx, K=128, N=32
__device__ __align__(16) u16   g_pBr[8192];           // root B: hprt, K=128, N=64
__device__ __align__(16) u16   g_pBx[36864];          // sw feat B: [pf^2 | pf], K=576, N=64
__device__ __align__(16) u16   g_pBs[36864];          // sw str  B: [qf^2 | qf], K=576, N=64

__device__ __forceinline__ float bf2f(u16 u) {
    union { unsigned u; float f; } v; v.u = ((unsigned)u) << 16; return v.f;
}
__device__ __forceinline__ u16 f2bf(float f) {
    __hip_bfloat16 h = __float2bfloat16(f);
    union { __hip_bfloat16 h; u16 u; } v; v.h = h; return v.u;
}
__device__ __forceinline__ float ldv(const void* p, int i, int f32) {
    return f32 ? ((const float*)p)[i] : bf2f(((const u16*)p)[i]);
}
__device__ __forceinline__ float sigmoidf(float x) { return 1.f / (1.f + expf(-x)); }

// B-fragment index: element (kd, ncol); lane = quad*16 + n holds B[kd=ks*32+quad*8+j][ncol]
__device__ __forceinline__ int bfrag_idx(int ksteps, int ncol, int kd) {
    int ntile = ncol >> 4, n = ncol & 15;
    int kstep = kd >> 5, quad = (kd >> 3) & 3, j = kd & 7;
    return ((ntile * ksteps + kstep) * 64 + quad * 16 + n) * 8 + j;
}

// branch-free stable rank of 9 values (tie -> lower original index first)
__device__ __forceinline__ void rank9(const float* v, int* r) {
#pragma unroll
    for (int m = 0; m < 9; m++) {
        int rk = 0;
#pragma unroll
        for (int n = 0; n < 9; n++)
            rk += (v[n] < v[m]) || (v[n] == v[m] && n < m);
        r[m] = rk;
    }
}

// ---------------- kernel A: normalize thetas + pack proj B table ----------------
__global__ __launch_bounds__(64) void k_prep(const void* theta_x, const void* theta_s,
                                             const void* xlg) {
    int t = threadIdx.x;
    const int f32 = (((const u16*)xlg)[0] == 0);
    if (t < 32) {
        float s = 0;
        for (int d = 0; d < 128; d++) { float v = ldv(theta_x, t * 128 + d, f32); s = fmaf(v, v, s); }
        float inv = 1.f / sqrtf(s);
        for (int d = 0; d < 128; d++) {
            float v = ldv(theta_x, t * 128 + d, f32) * inv;
            g_tnx[t * 128 + d] = v;
            g_pBt[bfrag_idx(4, t, d)] = f2bf(v);
        }
    } else {
        int l = t - 32;
        float s = 0;
        for (int j = 0; j < 9; j++) { float v = ldv(theta_s, l * 9 + j, f32); s = fmaf(v, v, s); }
        float inv = 1.f / sqrtf(s);
        for (int j = 0; j < 9; j++) g_tns[l * 9 + j] = ldv(theta_s, l * 9 + j, f32) * inv;
    }
}

// ---------------- kernel L: linear + LN for all (b, row) ----------------
__global__ __launch_bounds__(256) void k_lin(const void* feat, const int* idxs,
                                             const void* xlw, const void* xlb,
                                             const void* xlg, const void* xlbt, int B) {
    __shared__ float hsh[1280];
    int t = threadIdx.x;
    const int f32 = (((const u16*)xlg)[0] == 0);
    int d = t & 127, rh = t >> 7, lane = t & 63, w = t >> 6;

    unsigned wreg[64];
#pragma unroll
    for (int i = 0; i < 64; i++) {
        float w0 = ldv(xlw, (2 * i) * 128 + d, f32);
        float w1 = ldv(xlw, (2 * i + 1) * 128 + d, f32);
        wreg[i] = (unsigned)f2bf(w0) | (((unsigned)f2bf(w1)) << 16);
    }
    float bias = ldv(xlb, d, f32);
    float g0 = ldv(xlg, lane, f32), g1 = ldv(xlg, lane + 64, f32);
    float b0 = ldv(xlbt, lane, f32), b1 = ldv(xlbt, lane + 64, f32);

    for (int bi = 0; bi < NB; bi++) {
        int b = blockIdx.x * NB + bi;
        if (b >= B) break;
        float xr[5][2];
#pragma unroll
        for (int q = 0; q < 5; q++) {
            int r = rh + 2 * q;
            int id = idxs[b * 10 + r];
            if (id == NALL) { xr[q][0] = 0.f; xr[q][1] = 0.f; }
            else {
                xr[q][0] = ldv(feat, id * 128 + lane, f32);
                xr[q][1] = ldv(feat, id * 128 + 64 + lane, f32);
            }
        }
        float acc[5];
#pragma unroll
        for (int q = 0; q < 5; q++) acc[q] = bias;
#pragma unroll
        for (int c = 0; c < 128; c++) {
            unsigned wp = wreg[c >> 1];
            float wv = (c & 1) ? __uint_as_float(wp & 0xffff0000u)
                               : __uint_as_float(wp << 16);
#pragma unroll
            for (int q = 0; q < 5; q++) {
                int xv = __builtin_amdgcn_readlane(__float_as_int(xr[q][c >> 6]), c & 63);
                acc[q] = fmaf(__int_as_float(xv), wv, acc[q]);
            }
        }
#pragma unroll
        for (int q = 0; q < 5; q++) hsh[(rh + 2 * q) * 128 + d] = acc[q];
        __syncthreads();
        for (int r = w; r < 10; r += 4) {
            float v0 = hsh[r * 128 + lane], v1 = hsh[r * 128 + 64 + lane];
            float s = v0 + v1, q = v0 * v0 + v1 * v1;
#pragma unroll
            for (int m = 32; m >= 1; m >>= 1) { s += __shfl_xor(s, m); q += __shfl_xor(q, m); }
            float mu = s * (1.f / 128.f);
            float var = fmaxf(q * (1.f / 128.f) - mu * mu, 0.f);
            float rs = rsqrtf(var + 1e-5f);
            g_hx[(b * 10 + r) * 128 + lane]      = f2bf((v0 - mu) * rs * g0 + b0);
            g_hx[(b * 10 + r) * 128 + 64 + lane] = f2bf((v1 - mu) * rs * g1 + b1);
        }
        __syncthreads();
    }
}

// ---------------- kernel B: prototype-side precompute (64 blocks, 1 per k) ----------------
struct PSMem {
    u16   Wl[16384];
    float xs[1280];
    float tnx[LL * 129];
    float hX[1280];
    float tns[288];
    float hst[81], hsn[81], pbS[288], pbX[288];
};
__global__ __launch_bounds__(256) void k_proto(
    const void* xlw, const void* xlb, const void* xlg, const void* xlbt,
    const void* slg, const void* slb, const void* wn_w1,
    const void* proto_root, const void* proto_neigh,
    const void* proto_rad, const void* proto_dn) {
    __shared__ PSMem S;
    int k = blockIdx.x, t = threadIdx.x;
    const int f32 = (((const u16*)xlg)[0] == 0);

    for (int i = t; i < 16384; i += 256)
        S.Wl[i] = f32 ? f2bf(((const float*)xlw)[i]) : ((const u16*)xlw)[i];
    for (int i = t; i < 4096; i += 256) { int l = i >> 7, d = i & 127; S.tnx[l * 129 + d] = g_tnx[i]; }
    for (int i = t; i < 288; i += 256) S.tns[i] = g_tns[i];
    {
        int c = t & 127;
        for (int r = t >> 7; r < 10; r += 2)
            S.xs[r * 128 + c] = (r < 9) ? ldv(proto_neigh, (k * 9 + r) * 128 + c, f32)
                                        : ldv(proto_root, k * 128 + c, f32);
    }
    __syncthreads();
    {   // lin
        int d = t & 127, rh = t >> 7;
        float bias = ldv(xlb, d, f32);
        for (int r = rh; r < 10; r += 2) {
            float acc = bias;
            const float* xr2 = S.xs + r * 128;
#pragma unroll 8
            for (int c = 0; c < 128; ++c)
                acc = fmaf(xr2[c], bf2f(S.Wl[c * 128 + d]), acc);
            S.hX[r * 128 + d] = acc;
        }
    }
    __syncthreads();
    {   // LN
        int lane = t & 63, w = t >> 6;
        float g0 = ldv(xlg, lane, f32), g1 = ldv(xlg, lane + 64, f32);
        float b0 = ldv(xlbt, lane, f32), b1 = ldv(xlbt, lane + 64, f32);
        for (int r = w; r < 10; r += 4) {
            float v0 = S.hX[r * 128 + lane], v1 = S.hX[r * 128 + 64 + lane];
            float s = v0 + v1, q = v0 * v0 + v1 * v1;
#pragma unroll
            for (int m = 32; m >= 1; m >>= 1) { s += __shfl_xor(s, m); q += __shfl_xor(q, m); }
            float mu = s * (1.f / 128.f);
            float var = fmaxf(q * (1.f / 128.f) - mu * mu, 0.f);
            float rs = rsqrtf(var + 1e-5f);
            S.hX[r * 128 + lane]      = (v0 - mu) * rs * g0 + b0;
            S.hX[r * 128 + 64 + lane] = (v1 - mu) * rs * g1 + b1;
        }
    }
    __syncthreads();

    if (t < 128) g_pBr[bfrag_idx(4, k, t)] = f2bf(S.hX[9 * 128 + t]);   // packed root B
    if (t < 64) {
        float v0 = S.hX[9 * 128 + t], v1 = S.hX[9 * 128 + 64 + t];
        float q = v0 * v0 + v1 * v1;
#pragma unroll
        for (int m = 32; m >= 1; m >>= 1) q += __shfl_xor(q, m);
        if (t == 0) g_hprn[k] = q;
    }
    if (t < 32) {
        float acc = 0;
        for (int d = 0; d < 128; d++)
            acc = fmaf(S.hX[9 * 128 + d], ldv(wn_w1, (128 + d) * 32 + t, f32), acc);
        g_hpt[t * 64 + k] = acc;
    }
    {
        int l = t & 31;
        for (int m = t >> 5; m < 9; m += 8) {
            float acc = 0;
            const float* hr = S.hX + m * 128; const float* tr = S.tnx + l * 129;
#pragma unroll 8
            for (int d = 0; d < 128; d++) acc = fmaf(hr[d], tr[d], acc);
            S.pbX[m * 32 + l] = acc;
        }
    }
    __syncthreads();
    if (t < 32) {
        float v[9]; int r[9];
#pragma unroll
        for (int m = 0; m < 9; m++) v[m] = S.pbX[m * 32 + t];
        rank9(v, r);
#pragma unroll
        for (int m = 0; m < 9; m++) {
            int kd = t * 9 + r[m];
            g_pBx[bfrag_idx(18, k, kd)]       = f2bf(v[m] * v[m]);
            g_pBx[bfrag_idx(18, k, 288 + kd)] = f2bf(v[m]);
        }
    }
    if (t < 81) {
        int i = t / 9, j = t % 9; float v = 0.f;
        if (i != j) {
            int a = (i < j) ? i : j, b = (i < j) ? j : i;
            int p = a * 8 - a * (a - 1) / 2 + (b - a - 1);
            v = sigmoidf(ldv(proto_dn, p * 64 + k, f32));
        }
        S.hst[t] = v;
    }
    __syncthreads();
    if (t < 9) {
        float v[9]; int r[9];
#pragma unroll
        for (int i = 0; i < 9; i++) v[i] = S.hst[i * 9 + t];
        rank9(v, r);
#pragma unroll
        for (int i = 0; i < 9; i++) S.hst[r[i] * 9 + t] = v[i];
    }
    __syncthreads();
    if (t < 9) {
        float mu = 0;
#pragma unroll
        for (int j = 0; j < 9; j++) mu += S.hst[t * 9 + j];
        mu *= (1.f / 9.f);
        float var = 0;
#pragma unroll
        for (int j = 0; j < 9; j++) { float d0 = S.hst[t * 9 + j] - mu; var = fmaf(d0, d0, var); }
        var *= (1.f / 9.f);
        float rs = rsqrtf(var + 1e-5f);
#pragma unroll
        for (int j = 0; j < 9; j++)
            S.hsn[t * 9 + j] = (S.hst[t * 9 + j] - mu) * rs * ldv(slg, j, f32) + ldv(slb, j, f32);
    }
    __syncthreads();
    {
        int l = t & 31;
        for (int m = t >> 5; m < 9; m += 8) {
            float acc = 0;
#pragma unroll
            for (int j = 0; j < 9; j++) acc = fmaf(S.hsn[m * 9 + j], S.tns[l * 9 + j], acc);
            S.pbS[m * 32 + l] = acc;
        }
    }
    __syncthreads();
    if (t < 32) {
        float v[9]; int r[9];
#pragma unroll
        for (int m = 0; m < 9; m++) v[m] = S.pbS[m * 32 + t];
        rank9(v, r);
#pragma unroll
        for (int m = 0; m < 9; m++) {
            int kd = t * 9 + r[m];
            g_pBs[bfrag_idx(18, k, kd)]       = f2bf(v[m] * v[m]);
            g_pBs[bfrag_idx(18, k, 288 + kd)] = f2bf(v[m]);
        }
    }
    if (t == 0) {
        float v[9]; int r[9];
#pragma unroll
        for (int m = 0; m < 9; m++) v[m] = ldv(proto_rad, k * 9 + m, f32);
        rank9(v, r);
#pragma unroll
        for (int m = 0; m < 9; m++) g_rpst[r[m] * 64 + k] = v[m];
    }
}

// ---------------- main kernel: 1 block per b, wave-specialized, 3 barriers ----------------
struct M2 {
    u16   Cf[576];        // sw feat A row: [Wxw | -2*Ax]  (16B aligned: offset 0)
    u16   Cs[576];        // sw str  A row: [Wsw | -2*As]  (offset 1152)
    u16   hXb[1280];      // h rows bf16   (offset 2304)
    float pbX[288], pbS[288];
    float hst[81], hsn[81];
    float df[100];
    float dot[64], drad[64];
    float hbv[32], hpool[128];
    float rbss[9], wrad[9], vmsk[9];
    float sc[8];          // 0:n+eps 1:hrn 2:alpha 3:sum_t1x 4:sum_t1s
    unsigned adjr[10];
};
__global__ __launch_bounds__(256) void k_main(
    const void* adj, const int* idxs,
    const void* slg, const void* slb,
    const void* an_w1, const void* an_b1, const void* an_w2, const void* an_b2,
    const void* wn_w1, const void* wn_b1, const void* wn_w2, const void* wn_b2,
    const void* alpha_raw, const void* w_raw, const void* log_gamma,
    const void* xlg, void* out) {
    __shared__ __align__(16) M2 S;
    int b = blockIdx.x, t = threadIdx.x, lane = t & 63, w = t >> 6;
    const int f32 = (((const u16*)xlg)[0] == 0);
    int fm = lane & 15, quad = lane >> 4;

    // ================= B0 =================
    if (w == 0) {
        // stage h rows (bf16 raw copy as u32)
        const unsigned* src = (const unsigned*)(g_hx + b * 1280);
        unsigned* dst = (unsigned*)S.hXb;
        for (int i = lane; i < 640; i += 64) dst[i] = src[i];
    } else if (w == 1) {
        // feature projections via MFMA: D[m][l] = h_neigh[m] . tnx[l]
        f32x4 acc0 = {0.f, 0.f, 0.f, 0.f}, acc1 = {0.f, 0.f, 0.f, 0.f};
        const u16* arow = g_hx + (b * 10 + 1 + fm) * 128;
#pragma unroll
        for (int ks = 0; ks < 4; ks++) {
            short8 af = {0, 0, 0, 0, 0, 0, 0, 0};
            if (fm < 9) af = *(const short8*)(arow + ks * 32 + quad * 8);
            short8 b0 = *(const short8*)(g_pBt + ((0 * 4 + ks) * 64 + lane) * 8);
            short8 b1 = *(const short8*)(g_pBt + ((1 * 4 + ks) * 64 + lane) * 8);
            acc0 = MFMA(af, b0, acc0);
            acc1 = MFMA(af, b1, acc1);
        }
#pragma unroll
        for (int reg = 0; reg < 4; reg++) {
            int row = quad * 4 + reg;
            if (row < 9) {
                S.pbX[row * 32 + fm]      = acc0[reg];
                S.pbX[row * 32 + 16 + fm] = acc1[reg];
            }
        }
    } else if (w == 2) {
        // root-proto dots via MFMA: dot[k] = h_root . h_proto_root[k]
        f32x4 acc[4];
#pragma unroll
        for (int nt = 0; nt < 4; nt++) acc[nt] = (f32x4){0.f, 0.f, 0.f, 0.f};
        const u16* arow = g_hx + b * 10 * 128;
#pragma unroll
        for (int ks = 0; ks < 4; ks++) {
            short8 af = {0, 0, 0, 0, 0, 0, 0, 0};
            if (fm == 0) af = *(const short8*)(arow + ks * 32 + quad * 8);
#pragma unroll
            for (int nt = 0; nt < 4; nt++) {
                short8 bf = *(const short8*)(g_pBr + ((nt * 4 + ks) * 64 + lane) * 8);
                acc[nt] = MFMA(af, bf, acc[nt]);
            }
        }
        if (quad == 0) {
#pragma unroll
            for (int nt = 0; nt < 4; nt++) S.dot[nt * 16 + fm] = acc[nt][0];
        }
    } else {
        // masks, adjacency, BFS, radial
        bool valid = false;
        if (lane < 10) {
            int id = idxs[b * 10 + lane];
            valid = (lane == 0) || (id != NALL);
        }
        unsigned long long mb = __ballot(valid);
        if (lane >= 1 && lane < 10) S.vmsk[lane - 1] = ((mb >> lane) & 1) ? 1.f : 0.f;
        float nv = (float)__popcll(mb & 0x3FEull) + 1e-9f;
        if (lane == 0) S.sc[0] = nv;
        if (lane < 10) {
            unsigned row = 0;
            for (int j = 0; j < 10; j++)
                if (ldv(adj, b * 100 + lane * 10 + j, f32) > 1e-5f) row |= 1u << j;
            S.adjr[lane] = row;
        }
        if (lane < 10) {
            unsigned row = S.adjr[lane];
            int dl[10];
#pragma unroll
            for (int j = 0; j < 10; j++) dl[j] = (j == lane) ? 0 : (((row >> j) & 1) ? 1 : 10);
            unsigned reach = row | (1u << lane);
            for (int s = 2; s <= 9; s++) {
                unsigned nr = reach;
                for (int j = 0; j < 10; j++) if ((reach >> j) & 1) nr |= S.adjr[j];
                unsigned add = nr & ~reach;
                if (!add) break;
#pragma unroll
                for (int j = 0; j < 10; j++) if ((add >> j) & 1) dl[j] = s;
                reach = nr;
            }
            int mi = (int)((mb >> lane) & 1);
#pragma unroll
            for (int j = 0; j < 10; j++) {
                int mj = (int)((mb >> j) & 1);
                S.df[lane * 10 + j] = (mi && mj) ? (float)dl[j] * 0.1f : 1.0f;
            }
            if (lane == 0) {
                float v[9]; int r[9];
#pragma unroll
                for (int m = 0; m < 9; m++)
                    v[m] = ((mb >> (1 + m)) & 1) ? (float)dl[1 + m] * 0.1f : 1.0f;
                rank9(v, r);
                float inv = 1.f / nv;
#pragma unroll
                for (int m = 0; m < 9; m++) {
                    S.rbss[r[m]] = v[m];
                    S.wrad[r[m]] = (((mb >> (1 + m)) & 1) ? 1.f : 0.f) * inv;
                }
            }
        }
    }
    __syncthreads();

    // ================= B1 =================
    if (w == 0) {
        // structural chain: col-sort df -> LN -> proj -> per-l sort -> Cs
        if (lane < 9) {
            float v[9]; int r[9];
#pragma unroll
            for (int i = 0; i < 9; i++) v[i] = S.df[(1 + i) * 10 + 1 + lane];
            rank9(v, r);
#pragma unroll
            for (int i = 0; i < 9; i++) S.hst[r[i] * 9 + lane] = v[i];
        }
        if (lane < 9) {
            float mu = 0;
#pragma unroll
            for (int j = 0; j < 9; j++) mu += S.hst[lane * 9 + j];
            mu *= (1.f / 9.f);
            float var = 0;
#pragma unroll
            for (int j = 0; j < 9; j++) { float d0 = S.hst[lane * 9 + j] - mu; var = fmaf(d0, d0, var); }
            var *= (1.f / 9.f);
            float rs = rsqrtf(var + 1e-5f);
#pragma unroll
            for (int j = 0; j < 9; j++)
                S.hsn[lane * 9 + j] = (S.hst[lane * 9 + j] - mu) * rs * ldv(slg, j, f32) + ldv(slb, j, f32);
        }
        {
            int l = lane & 31;
            int m0 = (lane < 32) ? 0 : 5, m1 = (lane < 32) ? 5 : 9;
            for (int m = m0; m < m1; m++) {
                float a = 0;
#pragma unroll
                for (int j = 0; j < 9; j++) a = fmaf(S.hsn[m * 9 + j], g_tns[l * 9 + j], a);
                S.pbS[m * 32 + l] = a;
            }
        }
        float t1 = 0;
        if (lane < 32) {
            float v[9]; int r[9];
#pragma unroll
            for (int m = 0; m < 9; m++) v[m] = S.pbS[m * 32 + lane];
            rank9(v, r);
            float inv = 1.f / S.sc[0];
#pragma unroll
            for (int m = 0; m < 9; m++) {
                float wgt = S.vmsk[m] * inv;
                int slot = lane * 9 + r[m];
                S.Cs[slot]       = f2bf(wgt);
                S.Cs[288 + slot] = f2bf(-2.f * wgt * v[m]);
                t1 = fmaf(wgt * v[m], v[m], t1);
            }
        }
#pragma unroll
        for (int m = 16; m >= 1; m >>= 1) t1 += __shfl_xor(t1, m);
        if (lane == 0) S.sc[4] = t1;
    } else if (w == 1) {
        // feature per-l sort -> Cf
        float t1 = 0;
        if (lane < 32) {
            float v[9]; int r[9];
#pragma unroll
            for (int m = 0; m < 9; m++) v[m] = S.pbX[m * 32 + lane];
            rank9(v, r);
            float inv = 1.f / S.sc[0];
#pragma unroll
            for (int m = 0; m < 9; m++) {
                float wgt = S.vmsk[m] * inv;
                int slot = lane * 9 + r[m];
                S.Cf[slot]       = f2bf(wgt);
                S.Cf[288 + slot] = f2bf(-2.f * wgt * v[m]);
                t1 = fmaf(wgt * v[m], v[m], t1);
            }
        }
#pragma unroll
        for (int m = 16; m >= 1; m >>= 1) t1 += __shfl_xor(t1, m);
        if (lane == 0) S.sc[3] = t1;
    } else if (w == 2) {
        // ||h_root||^2, radial distances, pooled h, alpha MLP
        {
            float v0 = bf2f(S.hXb[lane]), v1 = bf2f(S.hXb[64 + lane]);
            float q = v0 * v0 + v1 * v1;
#pragma unroll
            for (int m = 32; m >= 1; m >>= 1) q += __shfl_xor(q, m);
            if (lane == 0) S.sc[1] = q;
        }
        {
            float acc = 0;
#pragma unroll
            for (int m = 0; m < 9; m++) {
                float d0 = S.rbss[m] - g_rpst[m * 64 + lane];
                acc = fmaf(d0 * d0, S.wrad[m], acc);
            }
            S.drad[lane] = acc;
        }
        {
            float inv = 1.f / S.sc[0];
            for (int dd = lane; dd < 128; dd += 64) {
                float a = 0;
#pragma unroll
                for (int m = 0; m < 9; m++)
                    a = fmaf(bf2f(S.hXb[(1 + m) * 128 + dd]), S.vmsk[m], a);
                S.hpool[dd] = a * inv;
            }
        }
        {
            int j = lane & 31, half = lane >> 5;
            float acc = 0;
            for (int d = half * 64; d < half * 64 + 64; d++)
                acc = fmaf(S.hpool[d], ldv(an_w1, d * 32 + j, f32), acc);
            acc += __shfl_xor(acc, 32);
            float red = 0;
            if (lane < 32)
                red = fmaxf(acc + ldv(an_b1, j, f32), 0.f) * ldv(an_w2, j, f32);
#pragma unroll
            for (int m = 16; m >= 1; m >>= 1) red += __shfl_xor(red, m);
            if (lane == 0)
                S.sc[2] = sigmoidf(ldv(alpha_raw, 0, f32) + red + ldv(an_b2, 0, f32));
        }
    } else {
        // hb = h_root @ wn_w1[:128] + wn_b1
        int j = lane & 31, half = lane >> 5;
        float acc = 0;
        for (int d = half * 64; d < half * 64 + 64; d++)
            acc = fmaf(bf2f(S.hXb[d]), ldv(wn_w1, d * 32 + j, f32), acc);
        acc += __shfl_xor(acc, 32);
        if (lane < 32) S.hbv[j] = acc + ldv(wn_b1, j, f32);
    }
    __syncthreads();

    // ================= B2: sliced-Wasserstein MFMA + epilogue =================
    {
        f32x4 accF = {0.f, 0.f, 0.f, 0.f}, accS = {0.f, 0.f, 0.f, 0.f};
#pragma unroll
        for (int ks = 0; ks < 18; ks++) {
            short8 aF = {0, 0, 0, 0, 0, 0, 0, 0}, aS = {0, 0, 0, 0, 0, 0, 0, 0};
            if (fm == 0) {
                aF = *(const short8*)(S.Cf + ks * 32 + quad * 8);
                aS = *(const short8*)(S.Cs + ks * 32 + quad * 8);
            }
            short8 bF = *(const short8*)(g_pBx + ((w * 18 + ks) * 64 + lane) * 8);
            short8 bS = *(const short8*)(g_pBs + ((w * 18 + ks) * 64 + lane) * 8);
            accF = MFMA(aF, bF, accF);
            accS = MFMA(aS, bS, accS);
        }
        if (quad == 0) {
            int k = w * 16 + fm;
            float swf = (S.sc[3] + accF[0]) * (1.f / 32.f);
            float sws = (S.sc[4] + accS[0]) * (1.f / 32.f);
            float drfk = S.sc[1] + g_hprn[k] - 2.f * S.dot[k];
            float wl = 0;
#pragma unroll 8
            for (int j = 0; j < 32; j++) {
                float vv = S.hbv[j] + g_hpt[j * 64 + k];
                wl = fmaf(fmaxf(vv, 0.f), ldv(wn_w2, j, f32), wl);
            }
            wl += ldv(wn_b2, 0, f32);
            float wgt = sigmoidf(ldv(w_raw, 0, f32) + wl);
            float dfeat = wgt * drfk + (1.f - wgt) * swf;
            float dstr  = wgt * S.drad[k] + (1.f - wgt) * sws;
            float al = S.sc[2];
            float dfgw = al * dfeat + (1.f - al) * dstr;
            if (!(dfgw == dfgw)) dfgw = 1e30f;
            float gamma = expf(ldv(log_gamma, 0, f32));
            float res = expf(-gamma * dfgw);
            if (f32) ((float*)out)[b * 64 + k] = res;
            else     ((u16*)out)[b * 64 + k] = f2bf(res);
        }
    }
}

extern "C" void kernel_launch(void* const* d_in, const int* in_sizes, int n_in,
                              void* d_out, int out_size, void* d_ws, size_t ws_size,
                              hipStream_t stream) {
    const void* adj  = d_in[0];
    const void* feat = d_in[1];
    const int*  idxs = (const int*)d_in[2];
    const void* xlw  = d_in[3];
    const void* xlb  = d_in[4];
    const void* xlg  = d_in[5];
    const void* xlbt = d_in[6];
    const void* slg  = d_in[7];
    const void* slb  = d_in[8];
    const void* thx  = d_in[9];
    const void* ths  = d_in[10];
    const void* araw = d_in[11];
    const void* anw1 = d_in[12];
    const void* anb1 = d_in[13];
    const void* anw2 = d_in[14];
    const void* anb2 = d_in[15];
    const void* wnw1 = d_in[16];
    const void* wnb1 = d_in[17];
    const void* wnw2 = d_in[18];
    const void* wnb2 = d_in[19];
    const void* wraw = d_in[20];
    const void* prt  = d_in[21];
    const void* prn  = d_in[22];
    const void* prad = d_in[23];
    const void* pdn  = d_in[24];
    const void* lgam = d_in[25];
    int B = in_sizes[2] / 10;

    k_prep<<<1, 64, 0, stream>>>(thx, ths, xlg);
    k_lin<<<(B + NB - 1) / NB, 256, 0, stream>>>(feat, idxs, xlw, xlb, xlg, xlbt, B);
    k_proto<<<64, 256, 0, stream>>>(xlw, xlb, xlg, xlbt, slg, slb, wnw1,
                                    prt, prn, prad, pdn);
    k_main<<<B, 256, 0, stream>>>(adj, idxs, slg, slb,
                                  anw1, anb1, anw2, anb2, wnw1, wnb1, wnw2, wnb2,
                                  araw, wraw, lgam, xlg, d_out);
}

// Round 7
// 358.567 us; speedup vs baseline: 2.5900x; 1.1856x over previous
//
#include <hip/hip_runtime.h>
#include <hip/hip_bf16.h>

typedef unsigned short u16;
typedef __attribute__((ext_vector_type(8))) short short8;   // 8 bf16 (4 VGPRs)
typedef __attribute__((ext_vector_type(4))) float f32x4;

#define NN 9
#define DX 128
#define KP 64
#define LL 32
#define NALL 100000
#define BMAX 8192
#define NBL 6

#define MFMA(a, b, c) __builtin_amdgcn_mfma_f32_16x16x32_bf16(a, b, c, 0, 0, 0)

// ---------- cross-kernel tables as typed device globals ----------
__device__ __align__(16) float g_tnx[LL * DX];        // normalized theta_x [l][d] (k_proto)
__device__ __align__(16) float g_tns[LL * NN];        // normalized theta_s [l][j]
__device__ __align__(16) float g_hprn[KP];            // ||h_proto_root||^2 [k]
__device__ __align__(16) float g_hpt[32 * KP];        // hp^T [j][k]
__device__ __align__(16) float g_rpst[NN * KP];       // sorted proto_rad [m][k]
__device__ __align__(16) u16   g_hx[BMAX * 10 * DX];  // LN'd h rows, bf16
// MFMA fragment-packed B tables (bf16)
__device__ __align__(16) u16   g_pBw[16384];          // x_lin_w B: K=128, N=128
__device__ __align__(16) u16   g_pBt[4096];           // proj B: tnx, K=128, N=32
__device__ __align__(16) u16   g_pBr[8192];           // root B: hprt, K=128, N=64
__device__ __align__(16) u16   g_pBx[36864];          // sw feat B: [pf^2 | pf], K=576, N=64
__device__ __align__(16) u16   g_pBs[36864];          // sw str  B: [qf^2 | qf], K=576, N=64

__device__ __forceinline__ float bf2f(u16 u) {
    union { unsigned u; float f; } v; v.u = ((unsigned)u) << 16; return v.f;
}
__device__ __forceinline__ u16 f2bf(float f) {
    __hip_bfloat16 h = __float2bfloat16(f);
    union { __hip_bfloat16 h; u16 u; } v; v.h = h; return v.u;
}
__device__ __forceinline__ float ldv(const void* p, int i, int f32) {
    return f32 ? ((const float*)p)[i] : bf2f(((const u16*)p)[i]);
}
__device__ __forceinline__ float sigmoidf(float x) { return 1.f / (1.f + expf(-x)); }

// B-fragment index: element (kd, ncol); lane = quad*16 + n holds B[kd=ks*32+quad*8+j][ncol]
__device__ __forceinline__ int bfrag_idx(int ksteps, int ncol, int kd) {
    int ntile = ncol >> 4, n = ncol & 15;
    int kstep = kd >> 5, quad = (kd >> 3) & 3, j = kd & 7;
    return ((ntile * ksteps + kstep) * 64 + quad * 16 + n) * 8 + j;
}

// branch-free stable rank of 9 values (tie -> lower original index first)
__device__ __forceinline__ void rank9(const float* v, int* r) {
#pragma unroll
    for (int m = 0; m < 9; m++) {
        int rk = 0;
#pragma unroll
        for (int n = 0; n < 9; n++)
            rk += (v[n] < v[m]) || (v[n] == v[m] && n < m);
        r[m] = rk;
    }
}

// ---------------- kernel A: normalize thetas + pack W / proj B tables ----------------
__global__ __launch_bounds__(256) void k_prep(const void* theta_x, const void* theta_s,
                                              const void* xlg, const void* xlw) {
    int t = threadIdx.x;
    const int f32 = (((const u16*)xlg)[0] == 0);
    for (int i = t; i < 16384; i += 256) {
        int c = i >> 7, d = i & 127;
        g_pBw[bfrag_idx(4, d, c)] = f2bf(ldv(xlw, i, f32));
    }
    if (t < 32) {
        float s = 0;
        for (int d = 0; d < 128; d++) { float v = ldv(theta_x, t * 128 + d, f32); s = fmaf(v, v, s); }
        float inv = 1.f / sqrtf(s);
        for (int d = 0; d < 128; d++) {
            float v = ldv(theta_x, t * 128 + d, f32) * inv;
            g_tnx[t * 128 + d] = v;
            g_pBt[bfrag_idx(4, t, d)] = f2bf(v);
        }
    } else if (t < 64) {
        int l = t - 32;
        float s = 0;
        for (int j = 0; j < 9; j++) { float v = ldv(theta_s, l * 9 + j, f32); s = fmaf(v, v, s); }
        float inv = 1.f / sqrtf(s);
        for (int j = 0; j < 9; j++) g_tns[l * 9 + j] = ldv(theta_s, l * 9 + j, f32) * inv;
    }
}

// ---------------- kernel L: linear + LN via MFMA ----------------
// 6 b's per block (60 rows); wave w owns A-tile rows w*16..w*16+15.
// Per kstep: 1 gathered 32B read per lane -> A-frag; 8 MFMA across N-tiles.
// LN fused on D-fragments (row = quad*4+reg, col = nt*16+fm).
__global__ __launch_bounds__(256) void k_lin(const void* feat, const int* idxs,
                                             const void* xlb, const void* xlg,
                                             const void* xlbt, int B) {
    int t = threadIdx.x, lane = t & 63, w = t >> 6;
    const int f32 = (((const u16*)xlg)[0] == 0);
    int fm = lane & 15, quad = lane >> 4;

    float bias[8], gg[8], bb[8];
#pragma unroll
    for (int nt = 0; nt < 8; nt++) {
        int col = nt * 16 + fm;
        bias[nt] = ldv(xlb, col, f32);
        gg[nt]   = ldv(xlg, col, f32);
        bb[nt]   = ldv(xlbt, col, f32);
    }

    int rowA = w * 16 + fm;
    int blA = rowA / 10, rA = rowA - blA * 10;
    int bA = blockIdx.x * NBL + blA;
    bool rvA = (blA < NBL) && (bA < B);
    int idA = rvA ? idxs[bA * 10 + rA] : NALL;

    f32x4 acc[8];
#pragma unroll
    for (int nt = 0; nt < 8; nt++) acc[nt] = (f32x4){0.f, 0.f, 0.f, 0.f};

#pragma unroll
    for (int ks = 0; ks < 4; ks++) {
        short8 af = {0, 0, 0, 0, 0, 0, 0, 0};
        if (idA != NALL) {
            if (f32) {
                const float* src = (const float*)feat + idA * 128 + ks * 32 + quad * 8;
                u16* ap = (u16*)&af;
#pragma unroll
                for (int j = 0; j < 8; j++) ap[j] = f2bf(src[j]);
            } else {
                af = *(const short8*)((const u16*)feat + idA * 128 + ks * 32 + quad * 8);
            }
        }
#pragma unroll
        for (int nt = 0; nt < 8; nt++) {
            short8 bf = *(const short8*)(g_pBw + ((nt * 4 + ks) * 64 + lane) * 8);
            acc[nt] = MFMA(af, bf, acc[nt]);
        }
    }
#pragma unroll
    for (int nt = 0; nt < 8; nt++)
#pragma unroll
        for (int reg = 0; reg < 4; reg++) acc[nt][reg] += bias[nt];

#pragma unroll
    for (int reg = 0; reg < 4; reg++) {
        float s = 0, q = 0;
#pragma unroll
        for (int nt = 0; nt < 8; nt++) {
            s += acc[nt][reg];
            q = fmaf(acc[nt][reg], acc[nt][reg], q);
        }
#pragma unroll
        for (int m = 1; m < 16; m <<= 1) { s += __shfl_xor(s, m); q += __shfl_xor(q, m); }
        float mu = s * (1.f / 128.f);
        float var = fmaxf(q * (1.f / 128.f) - mu * mu, 0.f);
        float rs = rsqrtf(var + 1e-5f);
        int rowD = w * 16 + quad * 4 + reg;
        int blD = rowD / 10, rD = rowD - blD * 10;
        int bD = blockIdx.x * NBL + blD;
        if (blD < NBL && bD < B) {
            u16* dst = g_hx + (bD * 10 + rD) * 128;
#pragma unroll
            for (int nt = 0; nt < 8; nt++)
                dst[nt * 16 + fm] = f2bf((acc[nt][reg] - mu) * rs * gg[nt] + bb[nt]);
        }
    }
}

// ---------------- kernel B: prototype-side precompute (64 blocks, 1 per k) ----------------
struct PSMem {
    u16   Wl[16384];
    float xs[1280];
    float tnx[LL * 129];
    float hX[1280];
    float tns[288];
    float hst[81], hsn[81], pbS[288], pbX[288];
};
__global__ __launch_bounds__(256) void k_proto(
    const void* xlw, const void* xlb, const void* xlg, const void* xlbt,
    const void* slg, const void* slb, const void* wn_w1,
    const void* proto_root, const void* proto_neigh,
    const void* proto_rad, const void* proto_dn) {
    __shared__ PSMem S;
    int k = blockIdx.x, t = threadIdx.x;
    const int f32 = (((const u16*)xlg)[0] == 0);

    for (int i = t; i < 16384; i += 256)
        S.Wl[i] = f32 ? f2bf(((const float*)xlw)[i]) : ((const u16*)xlw)[i];
    for (int i = t; i < 4096; i += 256) { int l = i >> 7, d = i & 127; S.tnx[l * 129 + d] = g_tnx[i]; }
    for (int i = t; i < 288; i += 256) S.tns[i] = g_tns[i];
    {
        int c = t & 127;
        for (int r = t >> 7; r < 10; r += 2)
            S.xs[r * 128 + c] = (r < 9) ? ldv(proto_neigh, (k * 9 + r) * 128 + c, f32)
                                        : ldv(proto_root, k * 128 + c, f32);
    }
    __syncthreads();
    {   // lin
        int d = t & 127, rh = t >> 7;
        float bias = ldv(xlb, d, f32);
        for (int r = rh; r < 10; r += 2) {
            float acc = bias;
            const float* xr2 = S.xs + r * 128;
#pragma unroll 8
            for (int c = 0; c < 128; ++c)
                acc = fmaf(xr2[c], bf2f(S.Wl[c * 128 + d]), acc);
            S.hX[r * 128 + d] = acc;
        }
    }
    __syncthreads();
    {   // LN
        int lane = t & 63, w = t >> 6;
        float g0 = ldv(xlg, lane, f32), g1 = ldv(xlg, lane + 64, f32);
        float b0 = ldv(xlbt, lane, f32), b1 = ldv(xlbt, lane + 64, f32);
        for (int r = w; r < 10; r += 4) {
            float v0 = S.hX[r * 128 + lane], v1 = S.hX[r * 128 + 64 + lane];
            float s = v0 + v1, q = v0 * v0 + v1 * v1;
#pragma unroll
            for (int m = 32; m >= 1; m >>= 1) { s += __shfl_xor(s, m); q += __shfl_xor(q, m); }
            float mu = s * (1.f / 128.f);
            float var = fmaxf(q * (1.f / 128.f) - mu * mu, 0.f);
            float rs = rsqrtf(var + 1e-5f);
            S.hX[r * 128 + lane]      = (v0 - mu) * rs * g0 + b0;
            S.hX[r * 128 + 64 + lane] = (v1 - mu) * rs * g1 + b1;
        }
    }
    __syncthreads();

    if (t < 128) g_pBr[bfrag_idx(4, k, t)] = f2bf(S.hX[9 * 128 + t]);
    if (t < 64) {
        float v0 = S.hX[9 * 128 + t], v1 = S.hX[9 * 128 + 64 + t];
        float q = v0 * v0 + v1 * v1;
#pragma unroll
        for (int m = 32; m >= 1; m >>= 1) q += __shfl_xor(q, m);
        if (t == 0) g_hprn[k] = q;
    }
    if (t < 32) {
        float acc = 0;
        for (int d = 0; d < 128; d++)
            acc = fmaf(S.hX[9 * 128 + d], ldv(wn_w1, (128 + d) * 32 + t, f32), acc);
        g_hpt[t * 64 + k] = acc;
    }
    {
        int l = t & 31;
        for (int m = t >> 5; m < 9; m += 8) {
            float acc = 0;
            const float* hr = S.hX + m * 128; const float* tr = S.tnx + l * 129;
#pragma unroll 8
            for (int d = 0; d < 128; d++) acc = fmaf(hr[d], tr[d], acc);
            S.pbX[m * 32 + l] = acc;
        }
    }
    __syncthreads();
    if (t < 32) {
        float v[9]; int r[9];
#pragma unroll
        for (int m = 0; m < 9; m++) v[m] = S.pbX[m * 32 + t];
        rank9(v, r);
#pragma unroll
        for (int m = 0; m < 9; m++) {
            int kd = t * 9 + r[m];
            g_pBx[bfrag_idx(18, k, kd)]       = f2bf(v[m] * v[m]);
            g_pBx[bfrag_idx(18, k, 288 + kd)] = f2bf(v[m]);
        }
    }
    if (t < 81) {
        int i = t / 9, j = t % 9; float v = 0.f;
        if (i != j) {
            int a = (i < j) ? i : j, b = (i < j) ? j : i;
            int p = a * 8 - a * (a - 1) / 2 + (b - a - 1);
            v = sigmoidf(ldv(proto_dn, p * 64 + k, f32));
        }
        S.hst[t] = v;
    }
    __syncthreads();
    if (t < 9) {
        float v[9]; int r[9];
#pragma unroll
        for (int i = 0; i < 9; i++) v[i] = S.hst[i * 9 + t];
        rank9(v, r);
#pragma unroll
        for (int i = 0; i < 9; i++) S.hst[r[i] * 9 + t] = v[i];
    }
    __syncthreads();
    if (t < 9) {
        float mu = 0;
#pragma unroll
        for (int j = 0; j < 9; j++) mu += S.hst[t * 9 + j];
        mu *= (1.f / 9.f);
        float var = 0;
#pragma unroll
        for (int j = 0; j < 9; j++) { float d0 = S.hst[t * 9 + j] - mu; var = fmaf(d0, d0, var); }
        var *= (1.f / 9.f);
        float rs = rsqrtf(var + 1e-5f);
#pragma unroll
        for (int j = 0; j < 9; j++)
            S.hsn[t * 9 + j] = (S.hst[t * 9 + j] - mu) * rs * ldv(slg, j, f32) + ldv(slb, j, f32);
    }
    __syncthreads();
    {
        int l = t & 31;
        for (int m = t >> 5; m < 9; m += 8) {
            float acc = 0;
#pragma unroll
            for (int j = 0; j < 9; j++) acc = fmaf(S.hsn[m * 9 + j], S.tns[l * 9 + j], acc);
            S.pbS[m * 32 + l] = acc;
        }
    }
    __syncthreads();
    if (t < 32) {
        float v[9]; int r[9];
#pragma unroll
        for (int m = 0; m < 9; m++) v[m] = S.pbS[m * 32 + t];
        rank9(v, r);
#pragma unroll
        for (int m = 0; m < 9; m++) {
            int kd = t * 9 + r[m];
            g_pBs[bfrag_idx(18, k, kd)]       = f2bf(v[m] * v[m]);
            g_pBs[bfrag_idx(18, k, 288 + kd)] = f2bf(v[m]);
        }
    }
    if (t == 0) {
        float v[9]; int r[9];
#pragma unroll
        for (int m = 0; m < 9; m++) v[m] = ldv(proto_rad, k * 9 + m, f32);
        rank9(v, r);
#pragma unroll
        for (int m = 0; m < 9; m++) g_rpst[r[m] * 64 + k] = v[m];
    }
}

// ---------------- main kernel: 1 block per b, wave-specialized, 3 barriers ----------------
struct M2 {
    u16   Cf[576];
    u16   Cs[576];
    u16   hXb[1280];
    float pbX[288], pbS[288];
    float hst[81], hsn[81];
    float df[100];
    float dot[64], drad[64];
    float hbv[32], hpool[128];
    float rbss[9], wrad[9], vmsk[9];
    float sc[8];
    unsigned adjr[10];
};
__global__ __launch_bounds__(256) void k_main(
    const void* adj, const int* idxs,
    const void* slg, const void* slb,
    const void* an_w1, const void* an_b1, const void* an_w2, const void* an_b2,
    const void* wn_w1, const void* wn_b1, const void* wn_w2, const void* wn_b2,
    const void* alpha_raw, const void* w_raw, const void* log_gamma,
    const void* xlg, void* out) {
    __shared__ __align__(16) M2 S;
    int b = blockIdx.x, t = threadIdx.x, lane = t & 63, w = t >> 6;
    const int f32 = (((const u16*)xlg)[0] == 0);
    int fm = lane & 15, quad = lane >> 4;

    // ================= B0 =================
    if (w == 0) {
        const unsigned* src = (const unsigned*)(g_hx + b * 1280);
        unsigned* dst = (unsigned*)S.hXb;
        for (int i = lane; i < 640; i += 64) dst[i] = src[i];
    } else if (w == 1) {
        f32x4 acc0 = {0.f, 0.f, 0.f, 0.f}, acc1 = {0.f, 0.f, 0.f, 0.f};
        const u16* arow = g_hx + (b * 10 + 1 + fm) * 128;
#pragma unroll
        for (int ks = 0; ks < 4; ks++) {
            short8 af = {0, 0, 0, 0, 0, 0, 0, 0};
            if (fm < 9) af = *(const short8*)(arow + ks * 32 + quad * 8);
            short8 b0 = *(const short8*)(g_pBt + ((0 * 4 + ks) * 64 + lane) * 8);
            short8 b1 = *(const short8*)(g_pBt + ((1 * 4 + ks) * 64 + lane) * 8);
            acc0 = MFMA(af, b0, acc0);
            acc1 = MFMA(af, b1, acc1);
        }
#pragma unroll
        for (int reg = 0; reg < 4; reg++) {
            int row = quad * 4 + reg;
            if (row < 9) {
                S.pbX[row * 32 + fm]      = acc0[reg];
                S.pbX[row * 32 + 16 + fm] = acc1[reg];
            }
        }
    } else if (w == 2) {
        f32x4 acc[4];
#pragma unroll
        for (int nt = 0; nt < 4; nt++) acc[nt] = (f32x4){0.f, 0.f, 0.f, 0.f};
        const u16* arow = g_hx + b * 10 * 128;
#pragma unroll
        for (int ks = 0; ks < 4; ks++) {
            short8 af = {0, 0, 0, 0, 0, 0, 0, 0};
            if (fm == 0) af = *(const short8*)(arow + ks * 32 + quad * 8);
#pragma unroll
            for (int nt = 0; nt < 4; nt++) {
                short8 bf = *(const short8*)(g_pBr + ((nt * 4 + ks) * 64 + lane) * 8);
                acc[nt] = MFMA(af, bf, acc[nt]);
            }
        }
        if (quad == 0) {
#pragma unroll
            for (int nt = 0; nt < 4; nt++) S.dot[nt * 16 + fm] = acc[nt][0];
        }
    } else {
        bool valid = false;
        if (lane < 10) {
            int id = idxs[b * 10 + lane];
            valid = (lane == 0) || (id != NALL);
        }
        unsigned long long mb = __ballot(valid);
        if (lane >= 1 && lane < 10) S.vmsk[lane - 1] = ((mb >> lane) & 1) ? 1.f : 0.f;
        float nv = (float)__popcll(mb & 0x3FEull) + 1e-9f;
        if (lane == 0) S.sc[0] = nv;
        if (lane < 10) {
            unsigned row = 0;
            for (int j = 0; j < 10; j++)
                if (ldv(adj, b * 100 + lane * 10 + j, f32) > 1e-5f) row |= 1u << j;
            S.adjr[lane] = row;
        }
        if (lane < 10) {
            unsigned row = S.adjr[lane];
            int dl[10];
#pragma unroll
            for (int j = 0; j < 10; j++) dl[j] = (j == lane) ? 0 : (((row >> j) & 1) ? 1 : 10);
            unsigned reach = row | (1u << lane);
            for (int s = 2; s <= 9; s++) {
                unsigned nr = reach;
                for (int j = 0; j < 10; j++) if ((reach >> j) & 1) nr |= S.adjr[j];
                unsigned add = nr & ~reach;
                if (!add) break;
#pragma unroll
                for (int j = 0; j < 10; j++) if ((add >> j) & 1) dl[j] = s;
                reach = nr;
            }
            int mi = (int)((mb >> lane) & 1);
#pragma unroll
            for (int j = 0; j < 10; j++) {
                int mj = (int)((mb >> j) & 1);
                S.df[lane * 10 + j] = (mi && mj) ? (float)dl[j] * 0.1f : 1.0f;
            }
            if (lane == 0) {
                float v[9]; int r[9];
#pragma unroll
                for (int m = 0; m < 9; m++)
                    v[m] = ((mb >> (1 + m)) & 1) ? (float)dl[1 + m] * 0.1f : 1.0f;
                rank9(v, r);
                float inv = 1.f / nv;
#pragma unroll
                for (int m = 0; m < 9; m++) {
                    S.rbss[r[m]] = v[m];
                    S.wrad[r[m]] = (((mb >> (1 + m)) & 1) ? 1.f : 0.f) * inv;
                }
            }
        }
    }
    __syncthreads();

    // ================= B1 =================
    if (w == 0) {
        if (lane < 9) {
            float v[9]; int r[9];
#pragma unroll
            for (int i = 0; i < 9; i++) v[i] = S.df[(1 + i) * 10 + 1 + lane];
            rank9(v, r);
#pragma unroll
            for (int i = 0; i < 9; i++) S.hst[r[i] * 9 + lane] = v[i];
        }
        if (lane < 9) {
            float mu = 0;
#pragma unroll
            for (int j = 0; j < 9; j++) mu += S.hst[lane * 9 + j];
            mu *= (1.f / 9.f);
            float var = 0;
#pragma unroll
            for (int j = 0; j < 9; j++) { float d0 = S.hst[lane * 9 + j] - mu; var = fmaf(d0, d0, var); }
            var *= (1.f / 9.f);
            float rs = rsqrtf(var + 1e-5f);
#pragma unroll
            for (int j = 0; j < 9; j++)
                S.hsn[lane * 9 + j] = (S.hst[lane * 9 + j] - mu) * rs * ldv(slg, j, f32) + ldv(slb, j, f32);
        }
        {
            int l = lane & 31;
            int m0 = (lane < 32) ? 0 : 5, m1 = (lane < 32) ? 5 : 9;
            for (int m = m0; m < m1; m++) {
                float a = 0;
#pragma unroll
                for (int j = 0; j < 9; j++) a = fmaf(S.hsn[m * 9 + j], g_tns[l * 9 + j], a);
                S.pbS[m * 32 + l] = a;
            }
        }
        float t1 = 0;
        if (lane < 32) {
            float v[9]; int r[9];
#pragma unroll
            for (int m = 0; m < 9; m++) v[m] = S.pbS[m * 32 + lane];
            rank9(v, r);
            float inv = 1.f / S.sc[0];
#pragma unroll
            for (int m = 0; m < 9; m++) {
                float wgt = S.vmsk[m] * inv;
                int slot = lane * 9 + r[m];
                S.Cs[slot]       = f2bf(wgt);
                S.Cs[288 + slot] = f2bf(-2.f * wgt * v[m]);
                t1 = fmaf(wgt * v[m], v[m], t1);
            }
        }
#pragma unroll
        for (int m = 16; m >= 1; m >>= 1) t1 += __shfl_xor(t1, m);
        if (lane == 0) S.sc[4] = t1;
    } else if (w == 1) {
        float t1 = 0;
        if (lane < 32) {
            float v[9]; int r[9];
#pragma unroll
            for (int m = 0; m < 9; m++) v[m] = S.pbX[m * 32 + lane];
            rank9(v, r);
            float inv = 1.f / S.sc[0];
#pragma unroll
            for (int m = 0; m < 9; m++) {
                float wgt = S.vmsk[m] * inv;
                int slot = lane * 9 + r[m];
                S.Cf[slot]       = f2bf(wgt);
                S.Cf[288 + slot] = f2bf(-2.f * wgt * v[m]);
                t1 = fmaf(wgt * v[m], v[m], t1);
            }
        }
#pragma unroll
        for (int m = 16; m >= 1; m >>= 1) t1 += __shfl_xor(t1, m);
        if (lane == 0) S.sc[3] = t1;
    } else if (w == 2) {
        {
            float v0 = bf2f(S.hXb[lane]), v1 = bf2f(S.hXb[64 + lane]);
            float q = v0 * v0 + v1 * v1;
#pragma unroll
            for (int m = 32; m >= 1; m >>= 1) q += __shfl_xor(q, m);
            if (lane == 0) S.sc[1] = q;
        }
        {
            float acc = 0;
#pragma unroll
            for (int m = 0; m < 9; m++) {
                float d0 = S.rbss[m] - g_rpst[m * 64 + lane];
                acc = fmaf(d0 * d0, S.wrad[m], acc);
            }
            S.drad[lane] = acc;
        }
        {
            float inv = 1.f / S.sc[0];
            for (int dd = lane; dd < 128; dd += 64) {
                float a = 0;
#pragma unroll
                for (int m = 0; m < 9; m++)
                    a = fmaf(bf2f(S.hXb[(1 + m) * 128 + dd]), S.vmsk[m], a);
                S.hpool[dd] = a * inv;
            }
        }
        {
            int j = lane & 31, half = lane >> 5;
            float acc = 0;
            for (int d = half * 64; d < half * 64 + 64; d++)
                acc = fmaf(S.hpool[d], ldv(an_w1, d * 32 + j, f32), acc);
            acc += __shfl_xor(acc, 32);
            float red = 0;
            if (lane < 32)
                red = fmaxf(acc + ldv(an_b1, j, f32), 0.f) * ldv(an_w2, j, f32);
#pragma unroll
            for (int m = 16; m >= 1; m >>= 1) red += __shfl_xor(red, m);
            if (lane == 0)
                S.sc[2] = sigmoidf(ldv(alpha_raw, 0, f32) + red + ldv(an_b2, 0, f32));
        }
    } else {
        int j = lane & 31, half = lane >> 5;
        float acc = 0;
        for (int d = half * 64; d < half * 64 + 64; d++)
            acc = fmaf(bf2f(S.hXb[d]), ldv(wn_w1, d * 32 + j, f32), acc);
        acc += __shfl_xor(acc, 32);
        if (lane < 32) S.hbv[j] = acc + ldv(wn_b1, j, f32);
    }
    __syncthreads();

    // ================= B2: sliced-Wasserstein MFMA + epilogue =================
    {
        f32x4 accF = {0.f, 0.f, 0.f, 0.f}, accS = {0.f, 0.f, 0.f, 0.f};
#pragma unroll
        for (int ks = 0; ks < 18; ks++) {
            short8 aF = {0, 0, 0, 0, 0, 0, 0, 0}, aS = {0, 0, 0, 0, 0, 0, 0, 0};
            if (fm == 0) {
                aF = *(const short8*)(S.Cf + ks * 32 + quad * 8);
                aS = *(const short8*)(S.Cs + ks * 32 + quad * 8);
            }
            short8 bF = *(const short8*)(g_pBx + ((w * 18 + ks) * 64 + lane) * 8);
            short8 bS = *(const short8*)(g_pBs + ((w * 18 + ks) * 64 + lane) * 8);
            accF = MFMA(aF, bF, accF);
            accS = MFMA(aS, bS, accS);
        }
        if (quad == 0) {
            int k = w * 16 + fm;
            float swf = (S.sc[3] + accF[0]) * (1.f / 32.f);
            float sws = (S.sc[4] + accS[0]) * (1.f / 32.f);
            float drfk = S.sc[1] + g_hprn[k] - 2.f * S.dot[k];
            float wl = 0;
#pragma unroll 8
            for (int j = 0; j < 32; j++) {
                float vv = S.hbv[j] + g_hpt[j * 64 + k];
                wl = fmaf(fmaxf(vv, 0.f), ldv(wn_w2, j, f32), wl);
            }
            wl += ldv(wn_b2, 0, f32);
            float wgt = sigmoidf(ldv(w_raw, 0, f32) + wl);
            float dfeat = wgt * drfk + (1.f - wgt) * swf;
            float dstr  = wgt * S.drad[k] + (1.f - wgt) * sws;
            float al = S.sc[2];
            float dfgw = al * dfeat + (1.f - al) * dstr;
            if (!(dfgw == dfgw)) dfgw = 1e30f;
            float gamma = expf(ldv(log_gamma, 0, f32));
            float res = expf(-gamma * dfgw);
            if (f32) ((float*)out)[b * 64 + k] = res;
            else     ((u16*)out)[b * 64 + k] = f2bf(res);
        }
    }
}

extern "C" void kernel_launch(void* const* d_in, const int* in_sizes, int n_in,
                              void* d_out, int out_size, void* d_ws, size_t ws_size,
                              hipStream_t stream) {
    const void* adj  = d_in[0];
    const void* feat = d_in[1];
    const int*  idxs = (const int*)d_in[2];
    const void* xlw  = d_in[3];
    const void* xlb  = d_in[4];
    const void* xlg  = d_in[5];
    const void* xlbt = d_in[6];
    const void* slg  = d_in[7];
    const void* slb  = d_in[8];
    const void* thx  = d_in[9];
    const void* ths  = d_in[10];
    const void* araw = d_in[11];
    const void* anw1 = d_in[12];
    const void* anb1 = d_in[13];
    const void* anw2 = d_in[14];
    const void* anb2 = d_in[15];
    const void* wnw1 = d_in[16];
    const void* wnb1 = d_in[17];
    const void* wnw2 = d_in[18];
    const void* wnb2 = d_in[19];
    const void* wraw = d_in[20];
    const void* prt  = d_in[21];
    const void* prn  = d_in[22];
    const void* prad = d_in[23];
    const void* pdn  = d_in[24];
    const void* lgam = d_in[25];
    int B = in_sizes[2] / 10;

    k_prep<<<1, 256, 0, stream>>>(thx, ths, xlg, xlw);
    k_lin<<<(B + NBL - 1) / NBL, 256, 0, stream>>>(feat, idxs, xlb, xlg, xlbt, B);
    k_proto<<<64, 256, 0, stream>>>(xlw, xlb, xlg, xlbt, slg, slb, wnw1,
                                    prt, prn, prad, pdn);
    k_main<<<B, 256, 0, stream>>>(adj, idxs, slg, slb,
                                  anw1, anb1, anw2, anb2, wnw1, wnb1, wnw2, wnb2,
                                  araw, wraw, lgam, xlg, d_out);
}

// Round 8
// 309.876 us; speedup vs baseline: 2.9970x; 1.1571x over previous
//
#include <hip/hip_runtime.h>
#include <hip/hip_bf16.h>

typedef unsigned short u16;
typedef __attribute__((ext_vector_type(8))) short short8;   // 8 bf16 (4 VGPRs)
typedef __attribute__((ext_vector_type(4))) float f32x4;

#define NN 9
#define DX 128
#define KP 64
#define LL 32
#define NALL 100000
#define BMAX 8192
#define NBM 4

#define MFMA(a, b, c) __builtin_amdgcn_mfma_f32_16x16x32_bf16(a, b, c, 0, 0, 0)

// ---------- cross-kernel tables ----------
__device__ __align__(16) float g_tns[LL * NN];        // normalized theta_s [l][j]
__device__ __align__(16) float g_hprn[KP];            // ||h_proto_root||^2 [k]
__device__ __align__(16) float g_hpt[32 * KP];        // hp^T [j][k]
__device__ __align__(16) float g_rpst[NN * KP];       // sorted proto_rad [m][k]
__device__ __align__(16) u16   g_hx[BMAX * 10 * DX];  // batch LN'd h rows, bf16
__device__ __align__(16) float g_hp[KP * 10 * DX];    // proto LN'd h rows, f32
// MFMA fragment-packed B tables (bf16)
__device__ __align__(16) u16   g_pBw[16384];          // x_lin_w: K=128, N=128
__device__ __align__(16) u16   g_pBt[4096];           // tnx:     K=128, N=32
__device__ __align__(16) u16   g_pBr[8192];           // hprt:    K=128, N=64
__device__ __align__(16) u16   g_pBx[36864];          // sw feat [pf^2|pf]: K=576, N=64
__device__ __align__(16) u16   g_pBs[36864];          // sw str  [qf^2|qf]: K=576, N=64

__device__ __forceinline__ float bf2f(u16 u) {
    union { unsigned u; float f; } v; v.u = ((unsigned)u) << 16; return v.f;
}
__device__ __forceinline__ u16 f2bf(float f) {
    __hip_bfloat16 h = __float2bfloat16(f);
    union { __hip_bfloat16 h; u16 u; } v; v.h = h; return v.u;
}
__device__ __forceinline__ float ldv(const void* p, long i, int f32) {
    return f32 ? ((const float*)p)[i] : bf2f(((const u16*)p)[i]);
}
__device__ __forceinline__ float sigmoidf(float x) { return 1.f / (1.f + expf(-x)); }

__device__ __forceinline__ int bfrag_idx(int ksteps, int ncol, int kd) {
    int ntile = ncol >> 4, n = ncol & 15;
    int kstep = kd >> 5, quad = (kd >> 3) & 3, j = kd & 7;
    return ((ntile * ksteps + kstep) * 64 + quad * 16 + n) * 8 + j;
}

__device__ __forceinline__ void rank9(const float* v, int* r) {
#pragma unroll
    for (int m = 0; m < 9; m++) {
        int rk = 0;
#pragma unroll
        for (int n = 0; n < 9; n++)
            rk += (v[n] < v[m]) || (v[n] == v[m] && n < m);
        r[m] = rk;
    }
}

// ---------------- kernel A: pack W/theta tables ----------------
__global__ __launch_bounds__(256) void k_prep(const void* theta_x, const void* theta_s,
                                              const void* xlg, const void* xlw) {
    int t = threadIdx.x;
    const int f32 = (((const u16*)xlg)[0] == 0);
    for (int i = t; i < 16384; i += 256) {
        int c = i >> 7, d = i & 127;
        g_pBw[bfrag_idx(4, d, c)] = f2bf(ldv(xlw, i, f32));
    }
    if (t < 32) {
        float s = 0;
        for (int d = 0; d < 128; d++) { float v = ldv(theta_x, t * 128 + d, f32); s = fmaf(v, v, s); }
        float inv = 1.f / sqrtf(s);
        for (int d = 0; d < 128; d++)
            g_pBt[bfrag_idx(4, t, d)] = f2bf(ldv(theta_x, t * 128 + d, f32) * inv);
    } else if (t < 64) {
        int l = t - 32;
        float s = 0;
        for (int j = 0; j < 9; j++) { float v = ldv(theta_s, l * 9 + j, f32); s = fmaf(v, v, s); }
        float inv = 1.f / sqrtf(s);
        for (int j = 0; j < 9; j++) g_tns[l * 9 + j] = ldv(theta_s, l * 9 + j, f32) * inv;
    }
}

// ---------------- kernel L: linear+LN via MFMA for batch rows AND proto rows ----------------
// 60 rows/block. Blocks [0,NBQ): batch (gather via idxs -> g_hx bf16).
// Blocks [NBQ, NBQ+11): proto rows (proto_neigh/proto_root -> g_hp f32).
__global__ __launch_bounds__(256) void k_lin(const void* feat, const int* idxs,
                                             const void* proto_root, const void* proto_neigh,
                                             const void* xlb, const void* xlg,
                                             const void* xlbt, int B, int NBQ) {
    int t = threadIdx.x, lane = t & 63, w = t >> 6;
    const int f32 = (((const u16*)xlg)[0] == 0);
    int fm = lane & 15, quad = lane >> 4;
    bool isProto = (blockIdx.x >= (unsigned)NBQ);
    int base = isProto ? (blockIdx.x - NBQ) * 60 : blockIdx.x * 60;
    int rowT = isProto ? KP * 10 : B * 10;

    float bias[8], gg[8], bb[8];
#pragma unroll
    for (int nt = 0; nt < 8; nt++) {
        int col = nt * 16 + fm;
        bias[nt] = ldv(xlb, col, f32);
        gg[nt]   = ldv(xlg, col, f32);
        bb[nt]   = ldv(xlbt, col, f32);
    }

    int lr = w * 16 + fm, gr = base + lr;
    bool azero = true;
    const void* abuf = feat; long aoff = 0;
    if (lr < 60 && gr < rowT) {
        if (!isProto) {
            int id = idxs[gr];
            if (id != NALL) { azero = false; aoff = (long)id * 128; }
        } else {
            int kk = gr / 10, rr = gr - kk * 10;
            azero = false;
            if (rr < 9) { abuf = proto_neigh; aoff = (long)(kk * 9 + rr) * 128; }
            else        { abuf = proto_root;  aoff = (long)kk * 128; }
        }
    }

    f32x4 acc[8];
#pragma unroll
    for (int nt = 0; nt < 8; nt++) acc[nt] = (f32x4){0.f, 0.f, 0.f, 0.f};
#pragma unroll
    for (int ks = 0; ks < 4; ks++) {
        short8 af = {0, 0, 0, 0, 0, 0, 0, 0};
        if (!azero) {
            u16* ap = (u16*)&af;
#pragma unroll
            for (int j = 0; j < 8; j++)
                ap[j] = f2bf(ldv(abuf, aoff + ks * 32 + quad * 8 + j, f32));
        }
#pragma unroll
        for (int nt = 0; nt < 8; nt++) {
            short8 bf = *(const short8*)(g_pBw + ((nt * 4 + ks) * 64 + lane) * 8);
            acc[nt] = MFMA(af, bf, acc[nt]);
        }
    }
#pragma unroll
    for (int nt = 0; nt < 8; nt++)
#pragma unroll
        for (int reg = 0; reg < 4; reg++) acc[nt][reg] += bias[nt];

#pragma unroll
    for (int reg = 0; reg < 4; reg++) {
        float s = 0, q = 0;
#pragma unroll
        for (int nt = 0; nt < 8; nt++) {
            s += acc[nt][reg];
            q = fmaf(acc[nt][reg], acc[nt][reg], q);
        }
#pragma unroll
        for (int m = 1; m < 16; m <<= 1) { s += __shfl_xor(s, m); q += __shfl_xor(q, m); }
        float mu = s * (1.f / 128.f);
        float var = fmaxf(q * (1.f / 128.f) - mu * mu, 0.f);
        float rs = rsqrtf(var + 1e-5f);
        int rowD = w * 16 + quad * 4 + reg, grD = base + rowD;
        if (rowD < 60 && grD < rowT) {
#pragma unroll
            for (int nt = 0; nt < 8; nt++) {
                float val = (acc[nt][reg] - mu) * rs * gg[nt] + bb[nt];
                if (!isProto) g_hx[grD * 128 + nt * 16 + fm] = f2bf(val);
                else          g_hp[grD * 128 + nt * 16 + fm] = val;
            }
        }
    }
}

// ---------------- kernel B: per-k prototype chain (reads g_hp) ----------------
struct PSMem {
    float hX[1280];
    float pbX[288], pbS[288];
    float hst[81], hsn[81];
};
__global__ __launch_bounds__(256) void k_proto(
    const void* slg, const void* slb, const void* wn_w1,
    const void* proto_rad, const void* proto_dn, const void* xlg) {
    __shared__ __align__(16) PSMem S;
    int k = blockIdx.x, t = threadIdx.x, lane = t & 63, w = t >> 6;
    const int f32 = (((const u16*)xlg)[0] == 0);
    int fm = lane & 15, quad = lane >> 4;

    for (int i = t; i < 1280; i += 256) S.hX[i] = g_hp[k * 1280 + i];
    __syncthreads();

    if (t < 128) g_pBr[bfrag_idx(4, k, t)] = f2bf(S.hX[9 * 128 + t]);
    if (w == 0) {
        float v0 = S.hX[9 * 128 + lane], v1 = S.hX[9 * 128 + 64 + lane];
        float q = v0 * v0 + v1 * v1;
#pragma unroll
        for (int m = 32; m >= 1; m >>= 1) q += __shfl_xor(q, m);
        if (lane == 0) g_hprn[k] = q;
    }
    if (t >= 128 && t < 160) {
        int j = t - 128;
        float acc = 0;
        for (int d = 0; d < 128; d++)
            acc = fmaf(S.hX[9 * 128 + d], ldv(wn_w1, (128 + d) * 32 + j, f32), acc);
        g_hpt[j * 64 + k] = acc;
    }
    if (t == 160) {
        float v[9]; int r[9];
#pragma unroll
        for (int m = 0; m < 9; m++) v[m] = ldv(proto_rad, k * 9 + m, f32);
        rank9(v, r);
#pragma unroll
        for (int m = 0; m < 9; m++) g_rpst[r[m] * 64 + k] = v[m];
    }
    if (w == 1) {   // feature proj MFMA
        f32x4 acc0 = {0.f, 0.f, 0.f, 0.f}, acc1 = {0.f, 0.f, 0.f, 0.f};
#pragma unroll
        for (int ks = 0; ks < 4; ks++) {
            short8 af = {0, 0, 0, 0, 0, 0, 0, 0};
            if (fm < 9) {
                u16* ap = (u16*)&af;
#pragma unroll
                for (int j = 0; j < 8; j++) ap[j] = f2bf(S.hX[fm * 128 + ks * 32 + quad * 8 + j]);
            }
            short8 b0 = *(const short8*)(g_pBt + ((0 * 4 + ks) * 64 + lane) * 8);
            short8 b1 = *(const short8*)(g_pBt + ((1 * 4 + ks) * 64 + lane) * 8);
            acc0 = MFMA(af, b0, acc0);
            acc1 = MFMA(af, b1, acc1);
        }
#pragma unroll
        for (int reg = 0; reg < 4; reg++) {
            int row = quad * 4 + reg;
            if (row < 9) {
                S.pbX[row * 32 + fm]      = acc0[reg];
                S.pbX[row * 32 + 16 + fm] = acc1[reg];
            }
        }
    }
    if (w == 3) {   // C build
        for (int i = lane; i < 81; i += 64) {
            int ii = i / 9, jj = i % 9; float v = 0.f;
            if (ii != jj) {
                int a = (ii < jj) ? ii : jj, b2 = (ii < jj) ? jj : ii;
                int p = a * 8 - a * (a - 1) / 2 + (b2 - a - 1);
                v = sigmoidf(ldv(proto_dn, p * 64 + k, f32));
            }
            S.hst[i] = v;
        }
    }
    __syncthreads();
    if (t < 9) {    // col sort C
        float v[9]; int r[9];
#pragma unroll
        for (int i = 0; i < 9; i++) v[i] = S.hst[i * 9 + t];
        rank9(v, r);
#pragma unroll
        for (int i = 0; i < 9; i++) S.hst[r[i] * 9 + t] = v[i];
    }
    if (t >= 32 && t < 64) {    // sort pbX -> pack g_pBx
        int l = t - 32;
        float v[9]; int r[9];
#pragma unroll
        for (int m = 0; m < 9; m++) v[m] = S.pbX[m * 32 + l];
        rank9(v, r);
#pragma unroll
        for (int m = 0; m < 9; m++) {
            int kd = l * 9 + r[m];
            g_pBx[bfrag_idx(18, k, kd)]       = f2bf(v[m] * v[m]);
            g_pBx[bfrag_idx(18, k, 288 + kd)] = f2bf(v[m]);
        }
    }
    __syncthreads();
    if (t < 9) {    // LN rows
        float mu = 0;
#pragma unroll
        for (int j = 0; j < 9; j++) mu += S.hst[t * 9 + j];
        mu *= (1.f / 9.f);
        float var = 0;
#pragma unroll
        for (int j = 0; j < 9; j++) { float d0 = S.hst[t * 9 + j] - mu; var = fmaf(d0, d0, var); }
        var *= (1.f / 9.f);
        float rs = rsqrtf(var + 1e-5f);
#pragma unroll
        for (int j = 0; j < 9; j++)
            S.hsn[t * 9 + j] = (S.hst[t * 9 + j] - mu) * rs * ldv(slg, j, f32) + ldv(slb, j, f32);
    }
    __syncthreads();
    if (t < 64) {   // structural projections
        int l = t & 31;
        int m0 = (t < 32) ? 0 : 5, m1 = (t < 32) ? 5 : 9;
        for (int m = m0; m < m1; m++) {
            float a = 0;
#pragma unroll
            for (int j = 0; j < 9; j++) a = fmaf(S.hsn[m * 9 + j], g_tns[l * 9 + j], a);
            S.pbS[m * 32 + l] = a;
        }
    }
    __syncthreads();
    if (t < 32) {   // sort pbS -> pack g_pBs
        float v[9]; int r[9];
#pragma unroll
        for (int m = 0; m < 9; m++) v[m] = S.pbS[m * 32 + t];
        rank9(v, r);
#pragma unroll
        for (int m = 0; m < 9; m++) {
            int kd = t * 9 + r[m];
            g_pBs[bfrag_idx(18, k, kd)]       = f2bf(v[m] * v[m]);
            g_pBs[bfrag_idx(18, k, 288 + kd)] = f2bf(v[m]);
        }
    }
}

// ---------------- main kernel: 4 b's per block, one wave per b ----------------
struct M3 {
    u16   Cf[NBM][576];     // [wgt | -2*wgt*v]
    u16   Cs[NBM][576];
    u16   hroot[NBM][128];
    float pb[NBM][288];     // pbX then pbS (sequenced)
    float df[NBM][100];
    float hst[NBM][81], hsn[NBM][81];
    float drad[NBM][64];
    float hbv[NBM][32];
    float hpool[NBM][128];
    float rbss[NBM][9], wrad[NBM][9];
    float sc[NBM][8];       // 1:hrn 2:alpha 3:t1x 4:t1s
};
__global__ __launch_bounds__(256) void k_main(
    const void* adj, const int* idxs,
    const void* slg, const void* slb,
    const void* an_w1, const void* an_b1, const void* an_w2, const void* an_b2,
    const void* wn_w1, const void* wn_b1, const void* wn_w2, const void* wn_b2,
    const void* alpha_raw, const void* w_raw, const void* log_gamma,
    const void* xlg, void* out, int B) {
    __shared__ __align__(16) M3 S;
    int t = threadIdx.x, lane = t & 63, w = t >> 6;
    const int f32 = (((const u16*)xlg)[0] == 0);
    int fm = lane & 15, quad = lane >> 4;
    int bw = blockIdx.x * NBM + w;
    bool bv = (bw < B);

    unsigned long long mb = 0; float nv = 1e-9f, inv = 0.f;
    int dl[10];
#pragma unroll
    for (int j = 0; j < 10; j++) dl[j] = 0;

    // ================= P0 (per wave, own b) =================
    if (bv) {
        bool valid = false;
        if (lane < 10) {
            int id = idxs[bw * 10 + lane];
            valid = (lane == 0) || (id != NALL);
        }
        mb = __ballot(valid);
        nv = (float)__popcll(mb & 0x3FEull) + 1e-9f;
        inv = 1.f / nv;
        // adjacency bits + BFS in registers via shuffles
        unsigned rowbits = 0;
        if (lane < 10) {
            for (int j = 0; j < 10; j++)
                if (ldv(adj, (long)bw * 100 + lane * 10 + j, f32) > 1e-5f) rowbits |= 1u << j;
        }
#pragma unroll
        for (int j = 0; j < 10; j++) dl[j] = (j == lane) ? 0 : (((rowbits >> j) & 1) ? 1 : 10);
        unsigned reach = (lane < 10) ? (rowbits | (1u << lane)) : 0u;
        for (int s = 2; s <= 9; s++) {
            unsigned nr = reach;
#pragma unroll
            for (int j = 0; j < 10; j++) {
                unsigned rj = __shfl(rowbits, j);
                if ((reach >> j) & 1) nr |= rj;
            }
            unsigned add = nr & ~reach;
#pragma unroll
            for (int j = 0; j < 10; j++) if ((add >> j) & 1) dl[j] = s;
            reach = nr;
            if (__all(add == 0)) break;
        }
        if (lane < 10) {
            int mi = (int)((mb >> lane) & 1);
#pragma unroll
            for (int j = 0; j < 10; j++) {
                int mj = (int)((mb >> j) & 1);
                S.df[w][lane * 10 + j] = (mi && mj) ? (float)dl[j] * 0.1f : 1.0f;
            }
            if (lane == 0) {
                float v[9]; int r[9];
#pragma unroll
                for (int m = 0; m < 9; m++)
                    v[m] = ((mb >> (1 + m)) & 1) ? (float)dl[1 + m] * 0.1f : 1.0f;
                rank9(v, r);
#pragma unroll
                for (int m = 0; m < 9; m++) {
                    S.rbss[w][r[m]] = v[m];
                    S.wrad[w][r[m]] = (((mb >> (1 + m)) & 1) ? 1.f : 0.f) * inv;
                }
            }
        }
        // root row stage + ||h_root||^2
        {
            u16 u0 = g_hx[bw * 1280 + lane], u1 = g_hx[bw * 1280 + 64 + lane];
            S.hroot[w][lane] = u0; S.hroot[w][64 + lane] = u1;
            float v0 = bf2f(u0), v1 = bf2f(u1);
            float q = v0 * v0 + v1 * v1;
#pragma unroll
            for (int m = 32; m >= 1; m >>= 1) q += __shfl_xor(q, m);
            if (lane == 0) S.sc[w][1] = q;
        }
        // pooled h
        for (int dd = lane; dd < 128; dd += 64) {
            float a = 0;
#pragma unroll
            for (int m = 0; m < 9; m++) {
                float hv = bf2f(g_hx[bw * 1280 + (1 + m) * 128 + dd]);
                float msk = ((mb >> (1 + m)) & 1) ? 1.f : 0.f;
                a = fmaf(hv, msk, a);
            }
            S.hpool[w][dd] = a * inv;
        }
        // feature projections MFMA (A from global g_hx)
        {
            f32x4 acc0 = {0.f, 0.f, 0.f, 0.f}, acc1 = {0.f, 0.f, 0.f, 0.f};
            const u16* arow = g_hx + (bw * 10 + 1 + fm) * 128;
#pragma unroll
            for (int ks = 0; ks < 4; ks++) {
                short8 af = {0, 0, 0, 0, 0, 0, 0, 0};
                if (fm < 9) af = *(const short8*)(arow + ks * 32 + quad * 8);
                short8 b0 = *(const short8*)(g_pBt + ((0 * 4 + ks) * 64 + lane) * 8);
                short8 b1 = *(const short8*)(g_pBt + ((1 * 4 + ks) * 64 + lane) * 8);
                acc0 = MFMA(af, b0, acc0);
                acc1 = MFMA(af, b1, acc1);
            }
#pragma unroll
            for (int reg = 0; reg < 4; reg++) {
                int row = quad * 4 + reg;
                if (row < 9) {
                    S.pb[w][row * 32 + fm]      = acc0[reg];
                    S.pb[w][row * 32 + 16 + fm] = acc1[reg];
                }
            }
        }
    }
    __syncthreads();   // SY1

    // ================= P1 (per wave, own b) =================
    if (bv) {
        // feature sort -> Cf, t1x
        float t1 = 0;
        if (lane < 32) {
            float v[9]; int r[9];
#pragma unroll
            for (int m = 0; m < 9; m++) v[m] = S.pb[w][m * 32 + lane];
            rank9(v, r);
#pragma unroll
            for (int m = 0; m < 9; m++) {
                float wgt = (((mb >> (1 + m)) & 1) ? 1.f : 0.f) * inv;
                int slot = lane * 9 + r[m];
                S.Cf[w][slot]       = f2bf(wgt);
                S.Cf[w][288 + slot] = f2bf(-2.f * wgt * v[m]);
                t1 = fmaf(wgt * v[m], v[m], t1);
            }
        }
#pragma unroll
        for (int m = 16; m >= 1; m >>= 1) t1 += __shfl_xor(t1, m);
        if (lane == 0) S.sc[w][3] = t1;
        // structural column sort
        if (lane < 9) {
            float v[9]; int r[9];
#pragma unroll
            for (int i = 0; i < 9; i++) v[i] = S.df[w][(1 + i) * 10 + 1 + lane];
            rank9(v, r);
#pragma unroll
            for (int i = 0; i < 9; i++) S.hst[w][r[i] * 9 + lane] = v[i];
        }
        // radial distances
        {
            float acc = 0;
#pragma unroll
            for (int m = 0; m < 9; m++) {
                float d0 = S.rbss[w][m] - g_rpst[m * 64 + lane];
                acc = fmaf(d0 * d0, S.wrad[w][m], acc);
            }
            S.drad[w][lane] = acc;
        }
        // alpha MLP
        {
            int j = lane & 31, half = lane >> 5;
            float acc = 0;
            for (int d = half * 64; d < half * 64 + 64; d++)
                acc = fmaf(S.hpool[w][d], ldv(an_w1, d * 32 + j, f32), acc);
            acc += __shfl_xor(acc, 32);
            float red = 0;
            if (lane < 32)
                red = fmaxf(acc + ldv(an_b1, j, f32), 0.f) * ldv(an_w2, j, f32);
#pragma unroll
            for (int m = 16; m >= 1; m >>= 1) red += __shfl_xor(red, m);
            if (lane == 0)
                S.sc[w][2] = sigmoidf(ldv(alpha_raw, 0, f32) + red + ldv(an_b2, 0, f32));
        }
        // hb MLP (reads root row from global)
        {
            int j = lane & 31, half = lane >> 5;
            float acc = 0;
            for (int d = half * 64; d < half * 64 + 64; d++)
                acc = fmaf(bf2f(g_hx[bw * 1280 + d]), ldv(wn_w1, d * 32 + j, f32), acc);
            acc += __shfl_xor(acc, 32);
            if (lane < 32) S.hbv[w][j] = acc + ldv(wn_b1, j, f32);
        }
    }
    __syncthreads();   // SY2

    // ================= P2: LN of sorted structural rows =================
    if (bv && lane < 9) {
        float mu = 0;
#pragma unroll
        for (int j = 0; j < 9; j++) mu += S.hst[w][lane * 9 + j];
        mu *= (1.f / 9.f);
        float var = 0;
#pragma unroll
        for (int j = 0; j < 9; j++) { float d0 = S.hst[w][lane * 9 + j] - mu; var = fmaf(d0, d0, var); }
        var *= (1.f / 9.f);
        float rs = rsqrtf(var + 1e-5f);
#pragma unroll
        for (int j = 0; j < 9; j++)
            S.hsn[w][lane * 9 + j] = (S.hst[w][lane * 9 + j] - mu) * rs * ldv(slg, j, f32) + ldv(slb, j, f32);
    }
    __syncthreads();   // SY3

    // ================= P3: structural projections =================
    if (bv) {
        int l = lane & 31;
        int m0 = (lane < 32) ? 0 : 5, m1 = (lane < 32) ? 5 : 9;
        for (int m = m0; m < m1; m++) {
            float a = 0;
#pragma unroll
            for (int j = 0; j < 9; j++) a = fmaf(S.hsn[w][m * 9 + j], g_tns[l * 9 + j], a);
            S.pb[w][m * 32 + l] = a;
        }
    }
    __syncthreads();   // SY4

    // ================= P4: structural sort -> Cs, t1s =================
    if (bv) {
        float t1 = 0;
        if (lane < 32) {
            float v[9]; int r[9];
#pragma unroll
            for (int m = 0; m < 9; m++) v[m] = S.pb[w][m * 32 + lane];
            rank9(v, r);
#pragma unroll
            for (int m = 0; m < 9; m++) {
                float wgt = (((mb >> (1 + m)) & 1) ? 1.f : 0.f) * inv;
                int slot = lane * 9 + r[m];
                S.Cs[w][slot]       = f2bf(wgt);
                S.Cs[w][288 + slot] = f2bf(-2.f * wgt * v[m]);
                t1 = fmaf(wgt * v[m], v[m], t1);
            }
        }
#pragma unroll
        for (int m = 16; m >= 1; m >>= 1) t1 += __shfl_xor(t1, m);
        if (lane == 0) S.sc[w][4] = t1;
    }
    __syncthreads();   // SY5

    // ================= P5: batched MFMA (wave = n-tile) + epilogue =================
    {
        // root dots: A rows 0..3 = 4 b's root vectors
        f32x4 rd = {0.f, 0.f, 0.f, 0.f};
#pragma unroll
        for (int ks = 0; ks < 4; ks++) {
            short8 af = {0, 0, 0, 0, 0, 0, 0, 0};
            if (fm < NBM) af = *(const short8*)(S.hroot[fm] + ks * 32 + quad * 8);
            short8 bf = *(const short8*)(g_pBr + ((w * 4 + ks) * 64 + lane) * 8);
            rd = MFMA(af, bf, rd);
        }
        // sliced-W: A rows 0..3 = 4 b's coefficient rows
        f32x4 accF = {0.f, 0.f, 0.f, 0.f}, accS = {0.f, 0.f, 0.f, 0.f};
#pragma unroll
        for (int ks = 0; ks < 18; ks++) {
            short8 aF = {0, 0, 0, 0, 0, 0, 0, 0}, aS = {0, 0, 0, 0, 0, 0, 0, 0};
            if (fm < NBM) {
                aF = *(const short8*)(S.Cf[fm] + ks * 32 + quad * 8);
                aS = *(const short8*)(S.Cs[fm] + ks * 32 + quad * 8);
            }
            short8 bF = *(const short8*)(g_pBx + ((w * 18 + ks) * 64 + lane) * 8);
            short8 bS = *(const short8*)(g_pBs + ((w * 18 + ks) * 64 + lane) * 8);
            accF = MFMA(aF, bF, accF);
            accS = MFMA(aS, bS, accS);
        }
        if (quad == 0) {
            int k = w * 16 + fm;
            float wl[NBM] = {0.f, 0.f, 0.f, 0.f};
#pragma unroll 4
            for (int j = 0; j < 32; j++) {
                float hptv = g_hpt[j * 64 + k];
                float w2v = ldv(wn_w2, j, f32);
#pragma unroll
                for (int reg = 0; reg < NBM; reg++)
                    wl[reg] = fmaf(fmaxf(S.hbv[reg][j] + hptv, 0.f), w2v, wl[reg]);
            }
            float wb2 = ldv(wn_b2, 0, f32);
            float wr  = ldv(w_raw, 0, f32);
            float gamma = expf(ldv(log_gamma, 0, f32));
            float hprnk = g_hprn[k];
#pragma unroll
            for (int reg = 0; reg < NBM; reg++) {
                int bb = blockIdx.x * NBM + reg;
                if (bb >= B) continue;
                float swf = (S.sc[reg][3] + accF[reg]) * (1.f / 32.f);
                float sws = (S.sc[reg][4] + accS[reg]) * (1.f / 32.f);
                float drfk = S.sc[reg][1] + hprnk - 2.f * rd[reg];
                float wgt = sigmoidf(wr + wl[reg] + wb2);
                float dfeat = wgt * drfk + (1.f - wgt) * swf;
                float dstr  = wgt * S.drad[reg][k] + (1.f - wgt) * sws;
                float al = S.sc[reg][2];
                float dfgw = al * dfeat + (1.f - al) * dstr;
                if (!(dfgw == dfgw)) dfgw = 1e30f;
                float res = expf(-gamma * dfgw);
                if (f32) ((float*)out)[bb * 64 + k] = res;
                else     ((u16*)out)[bb * 64 + k] = f2bf(res);
            }
        }
    }
}

extern "C" void kernel_launch(void* const* d_in, const int* in_sizes, int n_in,
                              void* d_out, int out_size, void* d_ws, size_t ws_size,
                              hipStream_t stream) {
    const void* adj  = d_in[0];
    const void* feat = d_in[1];
    const int*  idxs = (const int*)d_in[2];
    const void* xlw  = d_in[3];
    const void* xlb  = d_in[4];
    const void* xlg  = d_in[5];
    const void* xlbt = d_in[6];
    const void* slg  = d_in[7];
    const void* slb  = d_in[8];
    const void* thx  = d_in[9];
    const void* ths  = d_in[10];
    const void* araw = d_in[11];
    const void* anw1 = d_in[12];
    const void* anb1 = d_in[13];
    const void* anw2 = d_in[14];
    const void* anb2 = d_in[15];
    const void* wnw1 = d_in[16];
    const void* wnb1 = d_in[17];
    const void* wnw2 = d_in[18];
    const void* wnb2 = d_in[19];
    const void* wraw = d_in[20];
    const void* prt  = d_in[21];
    const void* prn  = d_in[22];
    const void* prad = d_in[23];
    const void* pdn  = d_in[24];
    const void* lgam = d_in[25];
    int B = in_sizes[2] / 10;
    int NBQ = (B * 10 + 59) / 60;
    int NBP = (KP * 10 + 59) / 60;

    k_prep<<<1, 256, 0, stream>>>(thx, ths, xlg, xlw);
    k_lin<<<NBQ + NBP, 256, 0, stream>>>(feat, idxs, prt, prn, xlb, xlg, xlbt, B, NBQ);
    k_proto<<<64, 256, 0, stream>>>(slg, slb, wnw1, prad, pdn, xlg);
    k_main<<<(B + NBM - 1) / NBM, 256, 0, stream>>>(adj, idxs, slg, slb,
                                  anw1, anb1, anw2, anb2, wnw1, wnb1, wnw2, wnb2,
                                  araw, wraw, lgam, xlg, d_out, B);
}

// Round 9
// 294.202 us; speedup vs baseline: 3.1566x; 1.0533x over previous
//
#include <hip/hip_runtime.h>
#include <hip/hip_bf16.h>

typedef unsigned short u16;
typedef __attribute__((ext_vector_type(8))) short short8;   // 8 bf16 (4 VGPRs)
typedef __attribute__((ext_vector_type(4))) float f32x4;

#define NN 9
#define DX 128
#define KP 64
#define LL 32
#define NALL 100000
#define BMAX 8192
#define NBM 4

#define MFMA(a, b, c) __builtin_amdgcn_mfma_f32_16x16x32_bf16(a, b, c, 0, 0, 0)

// ---------- cross-kernel tables ----------
__device__ __align__(16) float g_tns[LL * NN];        // normalized theta_s [l][j] (pub. by k_proto blk0)
__device__ __align__(16) float g_hprn[KP];            // ||h_proto_root||^2 [k]
__device__ __align__(16) float g_hpt[32 * KP];        // hp^T [j][k]
__device__ __align__(16) float g_rpst[NN * KP];       // sorted proto_rad [m][k]
__device__ __align__(16) u16   g_hx[BMAX * 10 * DX];  // batch LN'd h rows, bf16
__device__ __align__(16) float g_hp[KP * 10 * DX];    // proto LN'd h rows, f32
// MFMA fragment-packed B tables (bf16)
__device__ __align__(16) u16   g_pBt[4096];           // tnx:  K=128, N=32 (pub. by k_proto blk0)
__device__ __align__(16) u16   g_pBr[8192];           // hprt: K=128, N=64
__device__ __align__(16) u16   g_pBx[36864];          // sw feat [pf^2|pf]: K=576, N=64
__device__ __align__(16) u16   g_pBs[36864];          // sw str  [qf^2|qf]: K=576, N=64

__device__ __forceinline__ float bf2f(u16 u) {
    union { unsigned u; float f; } v; v.u = ((unsigned)u) << 16; return v.f;
}
__device__ __forceinline__ u16 f2bf(float f) {
    __hip_bfloat16 h = __float2bfloat16(f);
    union { __hip_bfloat16 h; u16 u; } v; v.h = h; return v.u;
}
__device__ __forceinline__ float ldv(const void* p, long i, int f32) {
    return f32 ? ((const float*)p)[i] : bf2f(((const u16*)p)[i]);
}
__device__ __forceinline__ float sigmoidf(float x) { return 1.f / (1.f + expf(-x)); }

__device__ __forceinline__ int bfrag_idx(int ksteps, int ncol, int kd) {
    int ntile = ncol >> 4, n = ncol & 15;
    int kstep = kd >> 5, quad = (kd >> 3) & 3, j = kd & 7;
    return ((ntile * ksteps + kstep) * 64 + quad * 16 + n) * 8 + j;
}

__device__ __forceinline__ void rank9(const float* v, int* r) {
#pragma unroll
    for (int m = 0; m < 9; m++) {
        int rk = 0;
#pragma unroll
        for (int n = 0; n < 9; n++)
            rk += (v[n] < v[m]) || (v[n] == v[m] && n < m);
        r[m] = rk;
    }
}

// ---------------- kernel L: linear+LN via MFMA; W packed in own LDS ----------------
// 60 rows/block. Blocks [0,NBQ): batch rows -> g_hx bf16; [NBQ,NBQ+11): proto rows -> g_hp f32.
__global__ __launch_bounds__(256) void k_lin(const void* feat, const int* idxs,
                                             const void* proto_root, const void* proto_neigh,
                                             const void* xlw, const void* xlb, const void* xlg,
                                             const void* xlbt, int B, int NBQ) {
    __shared__ __align__(16) u16 Wf[16384];
    int t = threadIdx.x, lane = t & 63, w = t >> 6;
    const int f32 = (((const u16*)xlg)[0] == 0);
    int fm = lane & 15, quad = lane >> 4;

    // pack x_lin_w into LDS B-fragment layout (one-time)
    for (int i = t; i < 16384; i += 256) {
        int c = i >> 7, d = i & 127;
        Wf[bfrag_idx(4, d, c)] = f2bf(ldv(xlw, i, f32));
    }

    bool isProto = (blockIdx.x >= (unsigned)NBQ);
    int base = isProto ? (blockIdx.x - NBQ) * 60 : blockIdx.x * 60;
    int rowT = isProto ? KP * 10 : B * 10;

    float bias[8], gg[8], bb[8];
#pragma unroll
    for (int nt = 0; nt < 8; nt++) {
        int col = nt * 16 + fm;
        bias[nt] = ldv(xlb, col, f32);
        gg[nt]   = ldv(xlg, col, f32);
        bb[nt]   = ldv(xlbt, col, f32);
    }

    int lr = w * 16 + fm, gr = base + lr;
    bool azero = true;
    const void* abuf = feat; long aoff = 0;
    if (lr < 60 && gr < rowT) {
        if (!isProto) {
            int id = idxs[gr];
            if (id != NALL) { azero = false; aoff = (long)id * 128; }
        } else {
            int kk = gr / 10, rr = gr - kk * 10;
            azero = false;
            if (rr < 9) { abuf = proto_neigh; aoff = (long)(kk * 9 + rr) * 128; }
            else        { abuf = proto_root;  aoff = (long)kk * 128; }
        }
    }
    __syncthreads();

    f32x4 acc[8];
#pragma unroll
    for (int nt = 0; nt < 8; nt++) acc[nt] = (f32x4){0.f, 0.f, 0.f, 0.f};
#pragma unroll
    for (int ks = 0; ks < 4; ks++) {
        short8 af = {0, 0, 0, 0, 0, 0, 0, 0};
        if (!azero) {
            if (f32) {
                const f32x4* src = (const f32x4*)((const float*)abuf + aoff + ks * 32 + quad * 8);
                f32x4 v0 = src[0], v1 = src[1];
                u16* ap = (u16*)&af;
#pragma unroll
                for (int j = 0; j < 4; j++) { ap[j] = f2bf(v0[j]); ap[4 + j] = f2bf(v1[j]); }
            } else {
                af = *(const short8*)((const u16*)abuf + aoff + ks * 32 + quad * 8);
            }
        }
#pragma unroll
        for (int nt = 0; nt < 8; nt++) {
            short8 bf = *(const short8*)(Wf + ((nt * 4 + ks) * 64 + lane) * 8);
            acc[nt] = MFMA(af, bf, acc[nt]);
        }
    }
#pragma unroll
    for (int nt = 0; nt < 8; nt++)
#pragma unroll
        for (int reg = 0; reg < 4; reg++) acc[nt][reg] += bias[nt];

#pragma unroll
    for (int reg = 0; reg < 4; reg++) {
        float s = 0, q = 0;
#pragma unroll
        for (int nt = 0; nt < 8; nt++) {
            s += acc[nt][reg];
            q = fmaf(acc[nt][reg], acc[nt][reg], q);
        }
#pragma unroll
        for (int m = 1; m < 16; m <<= 1) { s += __shfl_xor(s, m); q += __shfl_xor(q, m); }
        float mu = s * (1.f / 128.f);
        float var = fmaxf(q * (1.f / 128.f) - mu * mu, 0.f);
        float rs = rsqrtf(var + 1e-5f);
        int rowD = w * 16 + quad * 4 + reg, grD = base + rowD;
        if (rowD < 60 && grD < rowT) {
#pragma unroll
            for (int nt = 0; nt < 8; nt++) {
                float val = (acc[nt][reg] - mu) * rs * gg[nt] + bb[nt];
                if (!isProto) g_hx[grD * 128 + nt * 16 + fm] = f2bf(val);
                else          g_hp[grD * 128 + nt * 16 + fm] = val;
            }
        }
    }
}

// ---------------- kernel B: per-k prototype chain (reads g_hp; local theta pack) ----------------
struct PSMem {
    float hX[1280];
    float pbX[288], pbS[288];
    float hst[81], hsn[81];
    u16   pBtL[4096];
    float tnsL[288];
};
__global__ __launch_bounds__(256) void k_proto(
    const void* slg, const void* slb, const void* wn_w1,
    const void* proto_rad, const void* proto_dn,
    const void* theta_x, const void* theta_s, const void* xlg) {
    __shared__ __align__(16) PSMem S;
    int k = blockIdx.x, t = threadIdx.x, lane = t & 63, w = t >> 6;
    const int f32 = (((const u16*)xlg)[0] == 0);
    int fm = lane & 15, quad = lane >> 4;

    // local theta packing (waves 0..1) + hX staging (waves 1..3)
    if (t < 32) {
        float s = 0;
        for (int d = 0; d < 128; d++) { float v = ldv(theta_x, t * 128 + d, f32); s = fmaf(v, v, s); }
        float inv = 1.f / sqrtf(s);
        for (int d = 0; d < 128; d++)
            S.pBtL[bfrag_idx(4, t, d)] = f2bf(ldv(theta_x, t * 128 + d, f32) * inv);
    } else if (t < 64) {
        int l = t - 32;
        float s = 0;
        for (int j = 0; j < 9; j++) { float v = ldv(theta_s, l * 9 + j, f32); s = fmaf(v, v, s); }
        float inv = 1.f / sqrtf(s);
        for (int j = 0; j < 9; j++) S.tnsL[l * 9 + j] = ldv(theta_s, l * 9 + j, f32) * inv;
    }
    if (t >= 64) {
        for (int i = t - 64; i < 1280; i += 192) S.hX[i] = g_hp[k * 1280 + i];
    }
    __syncthreads();
    if (k == 0) {   // publish packed theta tables for k_main
        for (int i = t; i < 4096; i += 256) g_pBt[i] = S.pBtL[i];
        for (int i = t; i < 288; i += 256) g_tns[i] = S.tnsL[i];
    }

    if (t < 128) g_pBr[bfrag_idx(4, k, t)] = f2bf(S.hX[9 * 128 + t]);
    if (w == 0) {
        float v0 = S.hX[9 * 128 + lane], v1 = S.hX[9 * 128 + 64 + lane];
        float q = v0 * v0 + v1 * v1;
#pragma unroll
        for (int m = 32; m >= 1; m >>= 1) q += __shfl_xor(q, m);
        if (lane == 0) g_hprn[k] = q;
    }
    if (t >= 128 && t < 160) {
        int j = t - 128;
        float acc = 0;
        for (int d = 0; d < 128; d++)
            acc = fmaf(S.hX[9 * 128 + d], ldv(wn_w1, (128 + d) * 32 + j, f32), acc);
        g_hpt[j * 64 + k] = acc;
    }
    if (t == 160) {
        float v[9]; int r[9];
#pragma unroll
        for (int m = 0; m < 9; m++) v[m] = ldv(proto_rad, k * 9 + m, f32);
        rank9(v, r);
#pragma unroll
        for (int m = 0; m < 9; m++) g_rpst[r[m] * 64 + k] = v[m];
    }
    if (w == 1) {   // feature proj MFMA (B from local pBtL)
        f32x4 acc0 = {0.f, 0.f, 0.f, 0.f}, acc1 = {0.f, 0.f, 0.f, 0.f};
#pragma unroll
        for (int ks = 0; ks < 4; ks++) {
            short8 af = {0, 0, 0, 0, 0, 0, 0, 0};
            if (fm < 9) {
                u16* ap = (u16*)&af;
#pragma unroll
                for (int j = 0; j < 8; j++) ap[j] = f2bf(S.hX[fm * 128 + ks * 32 + quad * 8 + j]);
            }
            short8 b0 = *(const short8*)(S.pBtL + ((0 * 4 + ks) * 64 + lane) * 8);
            short8 b1 = *(const short8*)(S.pBtL + ((1 * 4 + ks) * 64 + lane) * 8);
            acc0 = MFMA(af, b0, acc0);
            acc1 = MFMA(af, b1, acc1);
        }
#pragma unroll
        for (int reg = 0; reg < 4; reg++) {
            int row = quad * 4 + reg;
            if (row < 9) {
                S.pbX[row * 32 + fm]      = acc0[reg];
                S.pbX[row * 32 + 16 + fm] = acc1[reg];
            }
        }
    }
    if (w == 3) {   // C build
        for (int i = lane; i < 81; i += 64) {
            int ii = i / 9, jj = i % 9; float v = 0.f;
            if (ii != jj) {
                int a = (ii < jj) ? ii : jj, b2 = (ii < jj) ? jj : ii;
                int p = a * 8 - a * (a - 1) / 2 + (b2 - a - 1);
                v = sigmoidf(ldv(proto_dn, p * 64 + k, f32));
            }
            S.hst[i] = v;
        }
    }
    __syncthreads();
    if (t < 9) {    // col sort C
        float v[9]; int r[9];
#pragma unroll
        for (int i = 0; i < 9; i++) v[i] = S.hst[i * 9 + t];
        rank9(v, r);
#pragma unroll
        for (int i = 0; i < 9; i++) S.hst[r[i] * 9 + t] = v[i];
    }
    if (t >= 32 && t < 64) {    // sort pbX -> pack g_pBx
        int l = t - 32;
        float v[9]; int r[9];
#pragma unroll
        for (int m = 0; m < 9; m++) v[m] = S.pbX[m * 32 + l];
        rank9(v, r);
#pragma unroll
        for (int m = 0; m < 9; m++) {
            int kd = l * 9 + r[m];
            g_pBx[bfrag_idx(18, k, kd)]       = f2bf(v[m] * v[m]);
            g_pBx[bfrag_idx(18, k, 288 + kd)] = f2bf(v[m]);
        }
    }
    __syncthreads();
    if (t < 9) {    // LN rows
        float mu = 0;
#pragma unroll
        for (int j = 0; j < 9; j++) mu += S.hst[t * 9 + j];
        mu *= (1.f / 9.f);
        float var = 0;
#pragma unroll
        for (int j = 0; j < 9; j++) { float d0 = S.hst[t * 9 + j] - mu; var = fmaf(d0, d0, var); }
        var *= (1.f / 9.f);
        float rs = rsqrtf(var + 1e-5f);
#pragma unroll
        for (int j = 0; j < 9; j++)
            S.hsn[t * 9 + j] = (S.hst[t * 9 + j] - mu) * rs * ldv(slg, j, f32) + ldv(slb, j, f32);
    }
    __syncthreads();
    if (t < 64) {   // structural projections
        int l = t & 31;
        int m0 = (t < 32) ? 0 : 5, m1 = (t < 32) ? 5 : 9;
        for (int m = m0; m < m1; m++) {
            float a = 0;
#pragma unroll
            for (int j = 0; j < 9; j++) a = fmaf(S.hsn[m * 9 + j], S.tnsL[l * 9 + j], a);
            S.pbS[m * 32 + l] = a;
        }
    }
    __syncthreads();
    if (t < 32) {   // sort pbS -> pack g_pBs
        float v[9]; int r[9];
#pragma unroll
        for (int m = 0; m < 9; m++) v[m] = S.pbS[m * 32 + t];
        rank9(v, r);
#pragma unroll
        for (int m = 0; m < 9; m++) {
            int kd = t * 9 + r[m];
            g_pBs[bfrag_idx(18, k, kd)]       = f2bf(v[m] * v[m]);
            g_pBs[bfrag_idx(18, k, 288 + kd)] = f2bf(v[m]);
        }
    }
}

// ---------------- main kernel: 4 b's per block, one wave per b ----------------
struct M3 {
    u16   Cf[NBM][576];     // [wgt | -2*wgt*v]
    u16   Cs[NBM][576];
    u16   hroot[NBM][128];
    float pb[NBM][288];
    float df[NBM][100];
    float hst[NBM][81], hsn[NBM][81];
    float drad[NBM][64];
    float hbv[NBM][32];
    float hpool[NBM][128];
    float rbss[NBM][9], wrad[NBM][9];
    float sc[NBM][8];       // 1:hrn 2:alpha 3:t1x 4:t1s
};
__global__ __launch_bounds__(256) void k_main(
    const void* adj, const int* idxs,
    const void* slg, const void* slb,
    const void* an_w1, const void* an_b1, const void* an_w2, const void* an_b2,
    const void* wn_w1, const void* wn_b1, const void* wn_w2, const void* wn_b2,
    const void* alpha_raw, const void* w_raw, const void* log_gamma,
    const void* xlg, void* out, int B) {
    __shared__ __align__(16) M3 S;
    int t = threadIdx.x, lane = t & 63, w = t >> 6;
    const int f32 = (((const u16*)xlg)[0] == 0);
    int fm = lane & 15, quad = lane >> 4;
    int bw = blockIdx.x * NBM + w;
    bool bv = (bw < B);

    unsigned long long mb = 0; float nv = 1e-9f, inv = 0.f;
    int dl[10];
#pragma unroll
    for (int j = 0; j < 10; j++) dl[j] = 0;

    // ================= P0 =================
    if (bv) {
        bool valid = false;
        if (lane < 10) {
            int id = idxs[bw * 10 + lane];
            valid = (lane == 0) || (id != NALL);
        }
        mb = __ballot(valid);
        nv = (float)__popcll(mb & 0x3FEull) + 1e-9f;
        inv = 1.f / nv;
        unsigned rowbits = 0;
        if (lane < 10) {
            for (int j = 0; j < 10; j++)
                if (ldv(adj, (long)bw * 100 + lane * 10 + j, f32) > 1e-5f) rowbits |= 1u << j;
        }
#pragma unroll
        for (int j = 0; j < 10; j++) dl[j] = (j == lane) ? 0 : (((rowbits >> j) & 1) ? 1 : 10);
        unsigned reach = (lane < 10) ? (rowbits | (1u << lane)) : 0u;
        for (int s = 2; s <= 9; s++) {
            unsigned nr = reach;
#pragma unroll
            for (int j = 0; j < 10; j++) {
                unsigned rj = __shfl(rowbits, j);
                if ((reach >> j) & 1) nr |= rj;
            }
            unsigned add = nr & ~reach;
#pragma unroll
            for (int j = 0; j < 10; j++) if ((add >> j) & 1) dl[j] = s;
            reach = nr;
            if (__all(add == 0)) break;
        }
        if (lane < 10) {
            int mi = (int)((mb >> lane) & 1);
#pragma unroll
            for (int j = 0; j < 10; j++) {
                int mj = (int)((mb >> j) & 1);
                S.df[w][lane * 10 + j] = (mi && mj) ? (float)dl[j] * 0.1f : 1.0f;
            }
            if (lane == 0) {
                float v[9]; int r[9];
#pragma unroll
                for (int m = 0; m < 9; m++)
                    v[m] = ((mb >> (1 + m)) & 1) ? (float)dl[1 + m] * 0.1f : 1.0f;
                rank9(v, r);
#pragma unroll
                for (int m = 0; m < 9; m++) {
                    S.rbss[w][r[m]] = v[m];
                    S.wrad[w][r[m]] = (((mb >> (1 + m)) & 1) ? 1.f : 0.f) * inv;
                }
            }
        }
        {
            u16 u0 = g_hx[bw * 1280 + lane], u1 = g_hx[bw * 1280 + 64 + lane];
            S.hroot[w][lane] = u0; S.hroot[w][64 + lane] = u1;
            float v0 = bf2f(u0), v1 = bf2f(u1);
            float q = v0 * v0 + v1 * v1;
#pragma unroll
            for (int m = 32; m >= 1; m >>= 1) q += __shfl_xor(q, m);
            if (lane == 0) S.sc[w][1] = q;
        }
        for (int dd = lane; dd < 128; dd += 64) {
            float a = 0;
#pragma unroll
            for (int m = 0; m < 9; m++) {
                float hv = bf2f(g_hx[bw * 1280 + (1 + m) * 128 + dd]);
                float msk = ((mb >> (1 + m)) & 1) ? 1.f : 0.f;
                a = fmaf(hv, msk, a);
            }
            S.hpool[w][dd] = a * inv;
        }
        {
            f32x4 acc0 = {0.f, 0.f, 0.f, 0.f}, acc1 = {0.f, 0.f, 0.f, 0.f};
            const u16* arow = g_hx + (bw * 10 + 1 + fm) * 128;
#pragma unroll
            for (int ks = 0; ks < 4; ks++) {
                short8 af = {0, 0, 0, 0, 0, 0, 0, 0};
                if (fm < 9) af = *(const short8*)(arow + ks * 32 + quad * 8);
                short8 b0 = *(const short8*)(g_pBt + ((0 * 4 + ks) * 64 + lane) * 8);
                short8 b1 = *(const short8*)(g_pBt + ((1 * 4 + ks) * 64 + lane) * 8);
                acc0 = MFMA(af, b0, acc0);
                acc1 = MFMA(af, b1, acc1);
            }
#pragma unroll
            for (int reg = 0; reg < 4; reg++) {
                int row = quad * 4 + reg;
                if (row < 9) {
                    S.pb[w][row * 32 + fm]      = acc0[reg];
                    S.pb[w][row * 32 + 16 + fm] = acc1[reg];
                }
            }
        }
    }
    __syncthreads();   // SY1

    // ================= P1 =================
    if (bv) {
        float t1 = 0;
        if (lane < 32) {
            float v[9]; int r[9];
#pragma unroll
            for (int m = 0; m < 9; m++) v[m] = S.pb[w][m * 32 + lane];
            rank9(v, r);
#pragma unroll
            for (int m = 0; m < 9; m++) {
                float wgt = (((mb >> (1 + m)) & 1) ? 1.f : 0.f) * inv;
                int slot = lane * 9 + r[m];
                S.Cf[w][slot]       = f2bf(wgt);
                S.Cf[w][288 + slot] = f2bf(-2.f * wgt * v[m]);
                t1 = fmaf(wgt * v[m], v[m], t1);
            }
        }
#pragma unroll
        for (int m = 16; m >= 1; m >>= 1) t1 += __shfl_xor(t1, m);
        if (lane == 0) S.sc[w][3] = t1;
        if (lane < 9) {
            float v[9]; int r[9];
#pragma unroll
            for (int i = 0; i < 9; i++) v[i] = S.df[w][(1 + i) * 10 + 1 + lane];
            rank9(v, r);
#pragma unroll
            for (int i = 0; i < 9; i++) S.hst[w][r[i] * 9 + lane] = v[i];
        }
        {
            float acc = 0;
#pragma unroll
            for (int m = 0; m < 9; m++) {
                float d0 = S.rbss[w][m] - g_rpst[m * 64 + lane];
                acc = fmaf(d0 * d0, S.wrad[w][m], acc);
            }
            S.drad[w][lane] = acc;
        }
        {
            int j = lane & 31, half = lane >> 5;
            float acc = 0;
            for (int d = half * 64; d < half * 64 + 64; d++)
                acc = fmaf(S.hpool[w][d], ldv(an_w1, d * 32 + j, f32), acc);
            acc += __shfl_xor(acc, 32);
            float red = 0;
            if (lane < 32)
                red = fmaxf(acc + ldv(an_b1, j, f32), 0.f) * ldv(an_w2, j, f32);
#pragma unroll
            for (int m = 16; m >= 1; m >>= 1) red += __shfl_xor(red, m);
            if (lane == 0)
                S.sc[w][2] = sigmoidf(ldv(alpha_raw, 0, f32) + red + ldv(an_b2, 0, f32));
        }
        {
            int j = lane & 31, half = lane >> 5;
            float acc = 0;
            for (int d = half * 64; d < half * 64 + 64; d++)
                acc = fmaf(bf2f(g_hx[bw * 1280 + d]), ldv(wn_w1, d * 32 + j, f32), acc);
            acc += __shfl_xor(acc, 32);
            if (lane < 32) S.hbv[w][j] = acc + ldv(wn_b1, j, f32);
        }
    }
    __syncthreads();   // SY2

    // ================= P2 =================
    if (bv && lane < 9) {
        float mu = 0;
#pragma unroll
        for (int j = 0; j < 9; j++) mu += S.hst[w][lane * 9 + j];
        mu *= (1.f / 9.f);
        float var = 0;
#pragma unroll
        for (int j = 0; j < 9; j++) { float d0 = S.hst[w][lane * 9 + j] - mu; var = fmaf(d0, d0, var); }
        var *= (1.f / 9.f);
        float rs = rsqrtf(var + 1e-5f);
#pragma unroll
        for (int j = 0; j < 9; j++)
            S.hsn[w][lane * 9 + j] = (S.hst[w][lane * 9 + j] - mu) * rs * ldv(slg, j, f32) + ldv(slb, j, f32);
    }
    __syncthreads();   // SY3

    // ================= P3 =================
    if (bv) {
        int l = lane & 31;
        int m0 = (lane < 32) ? 0 : 5, m1 = (lane < 32) ? 5 : 9;
        for (int m = m0; m < m1; m++) {
            float a = 0;
#pragma unroll
            for (int j = 0; j < 9; j++) a = fmaf(S.hsn[w][m * 9 + j], g_tns[l * 9 + j], a);
            S.pb[w][m * 32 + l] = a;
        }
    }
    __syncthreads();   // SY4

    // ================= P4 =================
    if (bv) {
        float t1 = 0;
        if (lane < 32) {
            float v[9]; int r[9];
#pragma unroll
            for (int m = 0; m < 9; m++) v[m] = S.pb[w][m * 32 + lane];
            rank9(v, r);
#pragma unroll
            for (int m = 0; m < 9; m++) {
                float wgt = (((mb >> (1 + m)) & 1) ? 1.f : 0.f) * inv;
                int slot = lane * 9 + r[m];
                S.Cs[w][slot]       = f2bf(wgt);
                S.Cs[w][288 + slot] = f2bf(-2.f * wgt * v[m]);
                t1 = fmaf(wgt * v[m], v[m], t1);
            }
        }
#pragma unroll
        for (int m = 16; m >= 1; m >>= 1) t1 += __shfl_xor(t1, m);
        if (lane == 0) S.sc[w][4] = t1;
    }
    __syncthreads();   // SY5

    // ================= P5: batched MFMA + epilogue =================
    {
        f32x4 rd = {0.f, 0.f, 0.f, 0.f};
#pragma unroll
        for (int ks = 0; ks < 4; ks++) {
            short8 af = {0, 0, 0, 0, 0, 0, 0, 0};
            if (fm < NBM) af = *(const short8*)(S.hroot[fm] + ks * 32 + quad * 8);
            short8 bf = *(const short8*)(g_pBr + ((w * 4 + ks) * 64 + lane) * 8);
            rd = MFMA(af, bf, rd);
        }
        f32x4 accF = {0.f, 0.f, 0.f, 0.f}, accS = {0.f, 0.f, 0.f, 0.f};
#pragma unroll
        for (int ks = 0; ks < 18; ks++) {
            short8 aF = {0, 0, 0, 0, 0, 0, 0, 0}, aS = {0, 0, 0, 0, 0, 0, 0, 0};
            if (fm < NBM) {
                aF = *(const short8*)(S.Cf[fm] + ks * 32 + quad * 8);
                aS = *(const short8*)(S.Cs[fm] + ks * 32 + quad * 8);
            }
            short8 bF = *(const short8*)(g_pBx + ((w * 18 + ks) * 64 + lane) * 8);
            short8 bS = *(const short8*)(g_pBs + ((w * 18 + ks) * 64 + lane) * 8);
            accF = MFMA(aF, bF, accF);
            accS = MFMA(aS, bS, accS);
        }
        if (quad == 0) {
            int k = w * 16 + fm;
            float wl[NBM] = {0.f, 0.f, 0.f, 0.f};
#pragma unroll 4
            for (int j = 0; j < 32; j++) {
                float hptv = g_hpt[j * 64 + k];
                float w2v = ldv(wn_w2, j, f32);
#pragma unroll
                for (int reg = 0; reg < NBM; reg++)
                    wl[reg] = fmaf(fmaxf(S.hbv[reg][j] + hptv, 0.f), w2v, wl[reg]);
            }
            float wb2 = ldv(wn_b2, 0, f32);
            float wr  = ldv(w_raw, 0, f32);
            float gamma = expf(ldv(log_gamma, 0, f32));
            float hprnk = g_hprn[k];
#pragma unroll
            for (int reg = 0; reg < NBM; reg++) {
                int bb = blockIdx.x * NBM + reg;
                if (bb >= B) continue;
                float swf = (S.sc[reg][3] + accF[reg]) * (1.f / 32.f);
                float sws = (S.sc[reg][4] + accS[reg]) * (1.f / 32.f);
                float drfk = S.sc[reg][1] + hprnk - 2.f * rd[reg];
                float wgt = sigmoidf(wr + wl[reg] + wb2);
                float dfeat = wgt * drfk + (1.f - wgt) * swf;
                float dstr  = wgt * S.drad[reg][k] + (1.f - wgt) * sws;
                float al = S.sc[reg][2];
                float dfgw = al * dfeat + (1.f - al) * dstr;
                if (!(dfgw == dfgw)) dfgw = 1e30f;
                float res = expf(-gamma * dfgw);
                if (f32) ((float*)out)[bb * 64 + k] = res;
                else     ((u16*)out)[bb * 64 + k] = f2bf(res);
            }
        }
    }
}

extern "C" void kernel_launch(void* const* d_in, const int* in_sizes, int n_in,
                              void* d_out, int out_size, void* d_ws, size_t ws_size,
                              hipStream_t stream) {
    const void* adj  = d_in[0];
    const void* feat = d_in[1];
    const int*  idxs = (const int*)d_in[2];
    const void* xlw  = d_in[3];
    const void* xlb  = d_in[4];
    const void* xlg  = d_in[5];
    const void* xlbt = d_in[6];
    const void* slg  = d_in[7];
    const void* slb  = d_in[8];
    const void* thx  = d_in[9];
    const void* ths  = d_in[10];
    const void* araw = d_in[11];
    const void* anw1 = d_in[12];
    const void* anb1 = d_in[13];
    const void* anw2 = d_in[14];
    const void* anb2 = d_in[15];
    const void* wnw1 = d_in[16];
    const void* wnb1 = d_in[17];
    const void* wnw2 = d_in[18];
    const void* wnb2 = d_in[19];
    const void* wraw = d_in[20];
    const void* prt  = d_in[21];
    const void* prn  = d_in[22];
    const void* prad = d_in[23];
    const void* pdn  = d_in[24];
    const void* lgam = d_in[25];
    int B = in_sizes[2] / 10;
    int NBQ = (B * 10 + 59) / 60;
    int NBP = (KP * 10 + 59) / 60;

    k_lin<<<NBQ + NBP, 256, 0, stream>>>(feat, idxs, prt, prn, xlw, xlb, xlg, xlbt, B, NBQ);
    k_proto<<<64, 256, 0, stream>>>(slg, slb, wnw1, prad, pdn, thx, ths, xlg);
    k_main<<<(B + NBM - 1) / NBM, 256, 0, stream>>>(adj, idxs, slg, slb,
                                  anw1, anb1, anw2, anb2, wnw1, wnb1, wnw2, wnb2,
                                  araw, wraw, lgam, xlg, d_out, B);
}